// Round 11
// baseline (1811.252 us; speedup 1.0000x reference)
//
#include <hip/hip_runtime.h>

typedef __bf16 v8bf __attribute__((ext_vector_type(8)));
typedef float  v4f  __attribute__((ext_vector_type(4)));
typedef unsigned short us8 __attribute__((ext_vector_type(8)));

__device__ __forceinline__ float bf2f(unsigned short u) {
    union { unsigned int i; float f; } v; v.i = ((unsigned int)u) << 16; return v.f;
}
__device__ __forceinline__ unsigned short f2bf(float f) {
    union { float f; unsigned int i; } v; v.f = f;
    return (unsigned short)((v.i + 0x7fffu + ((v.i >> 16) & 1u)) >> 16);
}
// address involution swizzle: XOR 16B-slot bits (4-6) with bits 7-9. Bijective.
__device__ __forceinline__ int sw(int b) { return b ^ (((b >> 7) & 7) << 4); }

// ------- transpose+downcast (row-major out): dst[n][k] = bf16(src[k][n]) ----
__global__ __launch_bounds__(256)
void transpose_f32_bf16(const float* __restrict__ src,
                        unsigned short* __restrict__ dst, int K, int N)
{
    __shared__ unsigned short tile[64][72];
    const int tid = threadIdx.x;
    const int c0 = blockIdx.x * 64, r0 = blockIdx.y * 64;
    const int tr = tid >> 2, tc4 = tid & 3;
    const float* sp = src + (size_t)(r0 + tr) * N + c0 + tc4 * 16;
#pragma unroll
    for (int j = 0; j < 4; ++j) {
        v4f f = *reinterpret_cast<const v4f*>(sp + j * 4);
#pragma unroll
        for (int e = 0; e < 4; ++e) tile[tr][tc4 * 16 + j * 4 + e] = f2bf(f[e]);
    }
    __syncthreads();
    const int ow = tid >> 3, och = tid & 7;
#pragma unroll
    for (int p = 0; p < 2; ++p) {
        int orow = p * 32 + ow;
        us8 o;
#pragma unroll
        for (int e = 0; e < 8; ++e) o[e] = tile[och * 8 + e][orow];
        *reinterpret_cast<us8*>(dst + (size_t)(c0 + orow) * K + r0 + och * 8) = o;
    }
}

// ------- transpose+downcast (TILED out): tile (nt=bx, kt=by) is 8KB contig,
// slot pre-swizzled so scan stage() reads linearly & LDS-read swizzle works.
__global__ __launch_bounds__(256)
void transpose_f32_bf16_tiled(const float* __restrict__ src,
                              unsigned short* __restrict__ dst, int N, int ktiles)
{
    __shared__ unsigned short tile[64][72];
    const int tid = threadIdx.x;
    const int c0 = blockIdx.x * 64, r0 = blockIdx.y * 64;
    const int tr = tid >> 2, tc4 = tid & 3;
    const float* sp = src + (size_t)(r0 + tr) * N + c0 + tc4 * 16;
#pragma unroll
    for (int j = 0; j < 4; ++j) {
        v4f f = *reinterpret_cast<const v4f*>(sp + j * 4);
#pragma unroll
        for (int e = 0; e < 4; ++e) tile[tr][tc4 * 16 + j * 4 + e] = f2bf(f[e]);
    }
    __syncthreads();
    const int ow = tid >> 3, och = tid & 7;
    unsigned short* tb = dst + ((size_t)blockIdx.x * ktiles + blockIdx.y) * 4096;
#pragma unroll
    for (int p = 0; p < 2; ++p) {
        int orow = p * 32 + ow;                     // n-in-tile (row)
        us8 o;
#pragma unroll
        for (int e = 0; e < 8; ++e) o[e] = tile[och * 8 + e][orow];
        *reinterpret_cast<us8*>(tb + orow * 64 + (och ^ (orow & 7)) * 8) = o;
    }
}

// ------- x fp32 -> bf16 ----------------------------------------------------
__global__ __launch_bounds__(256)
void cvt_x(const float* __restrict__ x, unsigned short* __restrict__ xb)
{
    int i = blockIdx.x * 256 + threadIdx.x;      // 655360 groups of 8
    if (i >= 655360) return;
    v4f f0 = *reinterpret_cast<const v4f*>(x + (size_t)i * 8);
    v4f f1 = *reinterpret_cast<const v4f*>(x + (size_t)i * 8 + 4);
    us8 o;
#pragma unroll
    for (int e = 0; e < 4; ++e) { o[e] = f2bf(f0[e]); o[4 + e] = f2bf(f1[e]); }
    *reinterpret_cast<us8*>(xb + (size_t)i * 8) = o;
}

// ------- generic GEMM (xU / linear); B transposed (BT[n][k]) ---------------
template<int BN, bool STORE_BF16, bool AF32, bool BF32>
__global__ __launch_bounds__(256, 2)
void gemm_bt(const void* __restrict__ Ap, int lda_lo, int lda_hi,
             const void* __restrict__ BTp, int ldb,
             void* __restrict__ Cout, int ldc,
             int ksub, long long csplit_stride)
{
    constexpr int FN  = BN / 32;
    constexpr int BCH = BN / 32;
    const int tid = threadIdx.x;
    const int lane = tid & 63, wid = tid >> 6;
    const int wr = wid >> 1, wc = wid & 1;
    const int nt = blockIdx.x, mt = blockIdx.y, kz = blockIdx.z;
    const int n0 = nt * BN;
    const int kstart = kz * ksub;

    __shared__ unsigned short smem[(64 + BN) * 64];
    char* As = reinterpret_cast<char*>(smem);
    char* Bs = reinterpret_cast<char*>(smem + 64 * 64);

    const unsigned short* A16 = (const unsigned short*)Ap;
    const float*          A32 = (const float*)Ap;
    const unsigned short* B16 = (const unsigned short*)BTp;
    const float*          B32 = (const float*)BTp;

    const int arow = AF32 ? (tid >> 2) : (tid >> 3);
    const int aq   = AF32 ? (tid & 3) : (tid & 7);
    const float* Ab32 = A32 + (size_t)arow * lda_lo + (size_t)mt * lda_hi + kstart + aq * 16;
    const unsigned short* Ab16 = A16 + (size_t)arow * lda_lo + (size_t)mt * lda_hi + kstart + aq * 8;
    const int brow = tid >> 3, bq = tid & 7;
    const float* Bb32 = B32 + (size_t)(n0 + brow) * ldb + kstart + bq * 8;
    const unsigned short* Bb16 = B16 + (size_t)(n0 + brow) * ldb + kstart + bq * 8;

    v4f fa[4];
    us8 ra[2];
    v4f fb[BCH][2];
    us8 rb[BCH];

    auto load = [&](int kk) {
        if (AF32) {
#pragma unroll
            for (int j = 0; j < 4; ++j)
                fa[j] = *reinterpret_cast<const v4f*>(Ab32 + kk + j * 4);
        } else {
#pragma unroll
            for (int p = 0; p < 2; ++p)
                ra[p] = *reinterpret_cast<const us8*>(Ab16 + (size_t)(p * 32) * lda_lo + kk);
        }
        if (BF32) {
#pragma unroll
            for (int p = 0; p < BCH; ++p) {
                fb[p][0] = *reinterpret_cast<const v4f*>(Bb32 + (size_t)(p * 32) * ldb + kk);
                fb[p][1] = *reinterpret_cast<const v4f*>(Bb32 + (size_t)(p * 32) * ldb + kk + 4);
            }
        } else {
#pragma unroll
            for (int p = 0; p < BCH; ++p)
                rb[p] = *reinterpret_cast<const us8*>(Bb16 + (size_t)(p * 32) * ldb + kk);
        }
    };
    auto stage = [&]() {
        if (AF32) {
#pragma unroll
            for (int h = 0; h < 2; ++h) {
                us8 v;
#pragma unroll
                for (int e = 0; e < 8; ++e) v[e] = f2bf(fa[h * 2 + (e >> 2)][e & 3]);
                *reinterpret_cast<us8*>(As + arow * 128 + (((aq * 2 + h) * 16) ^ ((arow & 7) << 4))) = v;
            }
        } else {
#pragma unroll
            for (int p = 0; p < 2; ++p)
                *reinterpret_cast<us8*>(As + (arow + p * 32) * 128 + ((aq * 16) ^ ((arow & 7) << 4))) = ra[p];
        }
#pragma unroll
        for (int p = 0; p < BCH; ++p) {
            us8 v;
            if (BF32) {
#pragma unroll
                for (int e = 0; e < 8; ++e) v[e] = f2bf(fb[p][e >> 2][e & 3]);
            } else v = rb[p];
            *reinterpret_cast<us8*>(Bs + (brow + p * 32) * 128 + ((bq * 16) ^ ((brow & 7) << 4))) = v;
        }
    };

    v4f z4 = {0.f, 0.f, 0.f, 0.f};
    v4f acc[2][FN];
#pragma unroll
    for (int i = 0; i < 2; ++i)
#pragma unroll
        for (int j = 0; j < FN; ++j) acc[i][j] = z4;

    const int l15 = lane & 15, l4 = lane >> 4;
    const int nk = ksub / 64;
    load(0);
    for (int it = 0; it < nk; ++it) {
        __syncthreads();
        stage();
        __syncthreads();
        if (it + 1 < nk) load((it + 1) * 64);
#pragma unroll
        for (int ks = 0; ks < 2; ++ks) {
            const int kb = (ks * 32 + l4 * 8) * 2;
            v8bf af[2], bfr[FN];
#pragma unroll
            for (int fm = 0; fm < 2; ++fm) {
                int row = wr * 32 + fm * 16 + l15;
                af[fm] = *reinterpret_cast<const v8bf*>(As + row * 128 + (kb ^ ((row & 7) << 4)));
            }
#pragma unroll
            for (int fn = 0; fn < FN; ++fn) {
                int row = wc * (BN / 2) + fn * 16 + l15;
                bfr[fn] = *reinterpret_cast<const v8bf*>(Bs + row * 128 + (kb ^ ((row & 7) << 4)));
            }
#pragma unroll
            for (int fm = 0; fm < 2; ++fm)
#pragma unroll
                for (int fn = 0; fn < FN; ++fn)
                    acc[fm][fn] = __builtin_amdgcn_mfma_f32_16x16x32_bf16(af[fm], bfr[fn], acc[fm][fn], 0, 0, 0);
        }
    }
    const long long m0 = (long long)mt * 64;
#pragma unroll
    for (int fm = 0; fm < 2; ++fm)
#pragma unroll
        for (int fn = 0; fn < FN; ++fn)
#pragma unroll
            for (int r = 0; r < 4; ++r) {
                long long row = m0 + wr * 32 + fm * 16 + l4 * 4 + r;
                long long col = n0 + wc * (BN / 2) + fn * 16 + l15;
                long long idx = (long long)kz * csplit_stride + row * ldc + col;
                if (STORE_BF16) reinterpret_cast<unsigned short*>(Cout)[idx] = f2bf(acc[fm][fn][r]);
                else            reinterpret_cast<float*>(Cout)[idx]          = acc[fm][fn][r];
            }
}

// ------- h0 step: split-K 4, 4-buf counted-vmcnt pipeline (proven R10) -----
#define KZ 4
__global__ __launch_bounds__(256, 2)
void scan_step(const unsigned short* __restrict__ A, int lda,
               const unsigned short* __restrict__ BTiles, int ktiles,
               int kper,
               const unsigned short* __restrict__ xu,
               unsigned short* __restrict__ hnext,
               unsigned short* __restrict__ Hbf, int t,
               float* __restrict__ part,
               unsigned int* __restrict__ tickets)
{
    const int tid = threadIdx.x, lane = tid & 63, wid = tid >> 6;
    const int wr = wid >> 1, wc = wid & 1;
    const int nt = blockIdx.x & 127, kz = blockIdx.x >> 7;
    const int n0 = nt * 64, kstart = kz * kper;
    const int l15 = lane & 15, l4 = lane >> 4;
    const int nit = kper >> 6;

    __shared__ unsigned short smem[32768];   // 64 KB: 4 bufs x (A 8KB + B 8KB)
    char* base = reinterpret_cast<char*>(smem);

    const int srow = tid >> 3, sq = tid & 7;
    const int gslot = sq ^ (srow & 7);
    const unsigned short* Asrc = A + (size_t)srow * lda + kstart + gslot * 8;
    const unsigned short* Bsrc = BTiles
        + ((size_t)(nt * ktiles + kz * (kper >> 6))) * 4096 + tid * 8;

    auto stage = [&](int buf, int it) {
        char* dA = base + buf * 16384 + wid * 1024;
        char* dB = dA + 8192;
        const int kk = it * 64;
#pragma unroll
        for (int p = 0; p < 2; ++p) {
            __builtin_amdgcn_global_load_lds(
                (const __attribute__((address_space(1))) void*)(Asrc + kk + (size_t)p * 32 * lda),
                (__attribute__((address_space(3))) void*)(dA + p * 4096), 16, 0, 0);
            __builtin_amdgcn_global_load_lds(
                (const __attribute__((address_space(1))) void*)(Bsrc + (size_t)it * 4096 + p * 2048),
                (__attribute__((address_space(3))) void*)(dB + p * 4096), 16, 0, 0);
        }
    };

    v4f acc00 = {0.f, 0.f, 0.f, 0.f};
    v4f acc01 = acc00, acc10 = acc00, acc11 = acc00;

    stage(0, 0); stage(1, 1); stage(2, 2);
    for (int it = 0; it < nit; ++it) {
        const int ahead = nit - 1 - it;
        if (ahead >= 2)      asm volatile("s_waitcnt vmcnt(8)" ::: "memory");
        else if (ahead == 1) asm volatile("s_waitcnt vmcnt(4)" ::: "memory");
        else                 asm volatile("s_waitcnt vmcnt(0)" ::: "memory");
        __builtin_amdgcn_s_barrier();
        __builtin_amdgcn_sched_barrier(0);
        if (it + 3 < nit) stage((it + 3) & 3, it + 3);
        const char* As = base + (it & 3) * 16384;
        const char* Bs = As + 8192;
#pragma unroll
        for (int ks = 0; ks < 2; ++ks) {
            const int kb = (ks * 32 + l4 * 8) * 2;
            v8bf a0, a1, b0, b1;
            { int row = wr * 32 + l15;      a0 = *reinterpret_cast<const v8bf*>(As + row * 128 + (kb ^ ((row & 7) << 4))); }
            { int row = wr * 32 + 16 + l15; a1 = *reinterpret_cast<const v8bf*>(As + row * 128 + (kb ^ ((row & 7) << 4))); }
            { int row = wc * 32 + l15;      b0 = *reinterpret_cast<const v8bf*>(Bs + row * 128 + (kb ^ ((row & 7) << 4))); }
            { int row = wc * 32 + 16 + l15; b1 = *reinterpret_cast<const v8bf*>(Bs + row * 128 + (kb ^ ((row & 7) << 4))); }
            acc00 = __builtin_amdgcn_mfma_f32_16x16x32_bf16(a0, b0, acc00, 0, 0, 0);
            acc01 = __builtin_amdgcn_mfma_f32_16x16x32_bf16(a0, b1, acc01, 0, 0, 0);
            acc10 = __builtin_amdgcn_mfma_f32_16x16x32_bf16(a1, b0, acc10, 0, 0, 0);
            acc11 = __builtin_amdgcn_mfma_f32_16x16x32_bf16(a1, b1, acc11, 0, 0, 0);
        }
    }

    float* mypart = part + (size_t)kz * 524288;
#pragma unroll
    for (int r = 0; r < 4; ++r) {
        int row0 = wr * 32 + l4 * 4 + r;
        int col0 = n0 + wc * 32 + l15;
        mypart[(size_t)row0 * 8192 + col0]             = acc00[r];
        mypart[(size_t)row0 * 8192 + col0 + 16]        = acc01[r];
        mypart[(size_t)(row0 + 16) * 8192 + col0]      = acc10[r];
        mypart[(size_t)(row0 + 16) * 8192 + col0 + 16] = acc11[r];
    }

    __shared__ int lastflag;
    __syncthreads();
    if (tid == 0) {
        unsigned int old = __hip_atomic_fetch_add(&tickets[nt], 1u,
                              __ATOMIC_ACQ_REL, __HIP_MEMORY_SCOPE_AGENT);
        lastflag = (old == KZ - 1);
    }
    __syncthreads();
    if (!lastflag) return;

    const int row = tid >> 2;
    const int c0 = n0 + (tid & 3) * 16;
    float pre[16];
    if (xu) {
        const us8* xp = reinterpret_cast<const us8*>(xu + (size_t)row * 8192 + c0);
        us8 x0 = xp[0], x1 = xp[1];
#pragma unroll
        for (int j = 0; j < 8; ++j) { pre[j] = bf2f(x0[j]); pre[8 + j] = bf2f(x1[j]); }
    } else {
#pragma unroll
        for (int j = 0; j < 16; ++j) pre[j] = 0.f;
    }
#pragma unroll
    for (int z = 0; z < KZ; ++z) {
        const float* pp = part + (size_t)z * 524288 + (size_t)row * 8192 + c0;
#pragma unroll
        for (int q = 0; q < 4; ++q) {
            v4f v = *reinterpret_cast<const v4f*>(pp + q * 4);
#pragma unroll
            for (int e = 0; e < 4; ++e) pre[q * 4 + e] += v[e];
        }
    }
    us8 o0, o1;
#pragma unroll
    for (int j = 0; j < 16; ++j) {
        unsigned short hb = f2bf(tanhf(pre[j]));
        if (j < 8) o0[j] = hb; else o1[j - 8] = hb;
        int col = c0 + j;
        Hbf[(((size_t)row * 20 + t) * 1024 + (col & 1023)) * 8 + (col >> 10)] = hb;
    }
    *reinterpret_cast<us8*>(hnext + (size_t)row * 8192 + c0)     = o0;
    *reinterpret_cast<us8*>(hnext + (size_t)row * 8192 + c0 + 8) = o1;
    if (tid == 0)
        __hip_atomic_store(&tickets[nt], 0u, __ATOMIC_RELAXED, __HIP_MEMORY_SCOPE_AGENT);
}

// ------- scan step v2: split-K 8, 2-buf 32KB LDS -> 4-5 blocks/CU (TLP) ----
// grid 1024 = 128 nt x 8 kz; per-iter: stage(next) | vmcnt(4) | bar | mfma | bar
#define KZ2 8
__global__ __launch_bounds__(256, 4)
void scan_step2(const unsigned short* __restrict__ A, int lda,
                const unsigned short* __restrict__ BTiles, int ktiles,
                int kper,
                const unsigned short* __restrict__ xu,
                unsigned short* __restrict__ hnext,
                unsigned short* __restrict__ Hbf, int t,
                float* __restrict__ part,                 // [8][64][8192]
                unsigned int* __restrict__ tickets)
{
    const int tid = threadIdx.x, lane = tid & 63, wid = tid >> 6;
    const int wr = wid >> 1, wc = wid & 1;
    const int nt = blockIdx.x & 127, kz = blockIdx.x >> 7;
    const int n0 = nt * 64, kstart = kz * kper;
    const int l15 = lane & 15, l4 = lane >> 4;
    const int nit = kper >> 6;

    __shared__ unsigned short smem[16384];   // 32 KB: 2 bufs x (A 8KB + B 8KB)
    char* base = reinterpret_cast<char*>(smem);

    const int srow = tid >> 3, sq = tid & 7;
    const int gslot = sq ^ (srow & 7);
    const unsigned short* Asrc = A + (size_t)srow * lda + kstart + gslot * 8;
    const unsigned short* Bsrc = BTiles
        + ((size_t)(nt * ktiles + kz * (kper >> 6))) * 4096 + tid * 8;

    auto stage = [&](int buf, int it) {
        char* dA = base + buf * 16384 + wid * 1024;
        char* dB = dA + 8192;
        const int kk = it * 64;
#pragma unroll
        for (int p = 0; p < 2; ++p) {
            __builtin_amdgcn_global_load_lds(
                (const __attribute__((address_space(1))) void*)(Asrc + kk + (size_t)p * 32 * lda),
                (__attribute__((address_space(3))) void*)(dA + p * 4096), 16, 0, 0);
            __builtin_amdgcn_global_load_lds(
                (const __attribute__((address_space(1))) void*)(Bsrc + (size_t)it * 4096 + p * 2048),
                (__attribute__((address_space(3))) void*)(dB + p * 4096), 16, 0, 0);
        }
    };

    v4f acc00 = {0.f, 0.f, 0.f, 0.f};
    v4f acc01 = acc00, acc10 = acc00, acc11 = acc00;

    stage(0, 0);
    for (int it = 0; it < nit; ++it) {
        const int cur = it & 1;
        if (it + 1 < nit) {
            stage(cur ^ 1, it + 1);                      // buf cur^1 freed by bar#2 of it-1
            asm volatile("s_waitcnt vmcnt(4)" ::: "memory");   // stage(it) landed
        } else {
            asm volatile("s_waitcnt vmcnt(0)" ::: "memory");
        }
        __builtin_amdgcn_s_barrier();                    // all waves' stage(it) landed
        __builtin_amdgcn_sched_barrier(0);
        const char* As = base + cur * 16384;
        const char* Bs = As + 8192;
#pragma unroll
        for (int ks = 0; ks < 2; ++ks) {
            const int kb = (ks * 32 + l4 * 8) * 2;
            v8bf a0, a1, b0, b1;
            { int row = wr * 32 + l15;      a0 = *reinterpret_cast<const v8bf*>(As + row * 128 + (kb ^ ((row & 7) << 4))); }
            { int row = wr * 32 + 16 + l15; a1 = *reinterpret_cast<const v8bf*>(As + row * 128 + (kb ^ ((row & 7) << 4))); }
            { int row = wc * 32 + l15;      b0 = *reinterpret_cast<const v8bf*>(Bs + row * 128 + (kb ^ ((row & 7) << 4))); }
            { int row = wc * 32 + 16 + l15; b1 = *reinterpret_cast<const v8bf*>(Bs + row * 128 + (kb ^ ((row & 7) << 4))); }
            acc00 = __builtin_amdgcn_mfma_f32_16x16x32_bf16(a0, b0, acc00, 0, 0, 0);
            acc01 = __builtin_amdgcn_mfma_f32_16x16x32_bf16(a0, b1, acc01, 0, 0, 0);
            acc10 = __builtin_amdgcn_mfma_f32_16x16x32_bf16(a1, b0, acc10, 0, 0, 0);
            acc11 = __builtin_amdgcn_mfma_f32_16x16x32_bf16(a1, b1, acc11, 0, 0, 0);
        }
        __builtin_amdgcn_s_barrier();                    // buf cur free for overwrite
    }

    float* mypart = part + (size_t)kz * 524288;
#pragma unroll
    for (int r = 0; r < 4; ++r) {
        int row0 = wr * 32 + l4 * 4 + r;
        int col0 = n0 + wc * 32 + l15;
        mypart[(size_t)row0 * 8192 + col0]             = acc00[r];
        mypart[(size_t)row0 * 8192 + col0 + 16]        = acc01[r];
        mypart[(size_t)(row0 + 16) * 8192 + col0]      = acc10[r];
        mypart[(size_t)(row0 + 16) * 8192 + col0 + 16] = acc11[r];
    }

    __shared__ int lastflag;
    __syncthreads();
    if (tid == 0) {
        unsigned int old = __hip_atomic_fetch_add(&tickets[nt], 1u,
                              __ATOMIC_ACQ_REL, __HIP_MEMORY_SCOPE_AGENT);
        lastflag = (old == KZ2 - 1);
    }
    __syncthreads();
    if (!lastflag) return;

    const int row = tid >> 2;
    const int c0 = n0 + (tid & 3) * 16;
    float pre[16];
    {
        const us8* xp = reinterpret_cast<const us8*>(xu + (size_t)row * 8192 + c0);
        us8 x0 = xp[0], x1 = xp[1];
#pragma unroll
        for (int j = 0; j < 8; ++j) { pre[j] = bf2f(x0[j]); pre[8 + j] = bf2f(x1[j]); }
    }
#pragma unroll
    for (int z = 0; z < KZ2; ++z) {
        const float* pp = part + (size_t)z * 524288 + (size_t)row * 8192 + c0;
#pragma unroll
        for (int q = 0; q < 4; ++q) {
            v4f v = *reinterpret_cast<const v4f*>(pp + q * 4);
#pragma unroll
            for (int e = 0; e < 4; ++e) pre[q * 4 + e] += v[e];
        }
    }
    us8 o0, o1;
#pragma unroll
    for (int j = 0; j < 16; ++j) {
        unsigned short hb = f2bf(tanhf(pre[j]));
        if (j < 8) o0[j] = hb; else o1[j - 8] = hb;
        int col = c0 + j;
        Hbf[(((size_t)row * 20 + t) * 1024 + (col & 1023)) * 8 + (col >> 10)] = hb;
    }
    *reinterpret_cast<us8*>(hnext + (size_t)row * 8192 + c0)     = o0;
    *reinterpret_cast<us8*>(hnext + (size_t)row * 8192 + c0 + 8) = o1;
    if (tid == 0)
        __hip_atomic_store(&tickets[nt], 0u, __ATOMIC_RELAXED, __HIP_MEMORY_SCOPE_AGENT);
}

// ------- weight conversion to GEMM k-order bf16 ----------------------------
__global__ __launch_bounds__(256)
void cvt_w1(const float* __restrict__ w, unsigned short* __restrict__ o,
            unsigned int* __restrict__ tickets)
{
    if (blockIdx.x == 0 && threadIdx.x < 128) tickets[threadIdx.x] = 0;
    int idx = blockIdx.x * 256 + threadIdx.x;    // 64*224
    if (idx >= 64 * 224) return;
    int co = idx / 224, k = idx % 224;
    int g = k >> 3, ci = k & 7;
    float v = 0.f;
    if (g < 27) {
        int dt = g / 9, rr = g % 9, dy = rr / 3, dx = rr % 3;
        v = w[(((co * 8 + ci) * 3 + dt) * 3 + dy) * 3 + dx];
    }
    o[idx] = f2bf(v);
}
__global__ __launch_bounds__(256)
void cvt_w2(const float* __restrict__ w, unsigned short* __restrict__ o)
{
    int idx = blockIdx.x * 256 + threadIdx.x;    // 128*3072
    if (idx >= 128 * 3072) return;
    int co = idx / 3072, k = idx % 3072;
    int g = k >> 6, ci = k & 63;
    int dt = g >> 4, dy = (g >> 2) & 3, dx = g & 3;
    o[idx] = f2bf(w[(((co * 64 + ci) * 3 + dt) * 4 + dy) * 4 + dx]);
}

// ------- conv1: H[b][t][1024][8] -> y1[b][t][256][64] ----------------------
__global__ __launch_bounds__(256, 2)
void conv1_kernel(const unsigned short* __restrict__ H,
                  const unsigned short* __restrict__ w1,  // [64][224]
                  const float* __restrict__ bias,
                  unsigned short* __restrict__ y1)
{
    const int b = blockIdx.x, t = blockIdx.y;
    const int tid = threadIdx.x, lane = tid & 63, wid = tid >> 6;
    __shared__ unsigned short in_s[3 * 33 * 33 * 8];   // 52272 B
    __shared__ unsigned short w_s[64 * 224];           // stride 448 B

    for (int i = tid; i < 13068; i += 256) reinterpret_cast<unsigned int*>(in_s)[i] = 0;
    __syncthreads();
    for (int idx = tid; idx < 3 * 1024; idx += 256) {
        int dt = idx >> 10, rem = idx & 1023;
        int iy = rem >> 5, ix = rem & 31;
        int ts = t + dt - 1;
        if (ts >= 0 && ts < 20) {
            us8 v = *reinterpret_cast<const us8*>(H + (((size_t)b * 20 + ts) * 1024 + rem) * 8);
            int byte = ((dt * 33 + iy + 1) * 33 + (ix + 1)) * 16;
            *reinterpret_cast<us8*>(reinterpret_cast<char*>(in_s) + sw(byte)) = v;
        }
    }
    for (int idx = tid; idx < 64 * 28; idx += 256) {
        int co = idx / 28, j = idx % 28;
        us8 v = *reinterpret_cast<const us8*>(w1 + co * 224 + j * 8);
        *reinterpret_cast<us8*>(reinterpret_cast<char*>(w_s) + sw(co * 448 + j * 16)) = v;
    }
    __syncthreads();

    const int l15 = lane & 15, l4 = lane >> 4;
    const int m_lo = wid * 64 + l15;
    v4f z4 = {0.f, 0.f, 0.f, 0.f};
    v4f acc[4][4];                              // [fm][fc]
#pragma unroll
    for (int i = 0; i < 4; ++i)
#pragma unroll
        for (int j = 0; j < 4; ++j) acc[i][j] = z4;

#pragma unroll
    for (int ks = 0; ks < 7; ++ks) {
        int g = ks * 4 + l4;
        int gc = g < 27 ? g : 26;               // pad group: weights are zero
        int dt = gc / 9, rr = gc % 9, dy = rr / 3, dx = rr % 3;
        v8bf ap[4], aw[4];
#pragma unroll
        for (int fm = 0; fm < 4; ++fm) {
            int m = fm * 16 + m_lo;
            int py = m >> 4, px = m & 15;
            int byte = ((dt * 33 + 2 * py + dy) * 33 + 2 * px + dx) * 16;
            ap[fm] = *reinterpret_cast<const v8bf*>(reinterpret_cast<const char*>(in_s) + sw(byte));
        }
        int kb2 = (ks * 32 + l4 * 8) * 2;
#pragma unroll
        for (int fc = 0; fc < 4; ++fc) {
            int co = fc * 16 + l15;
            aw[fc] = *reinterpret_cast<const v8bf*>(reinterpret_cast<const char*>(w_s) + sw(co * 448 + kb2));
        }
#pragma unroll
        for (int fm = 0; fm < 4; ++fm)
#pragma unroll
            for (int fc = 0; fc < 4; ++fc)
                acc[fm][fc] = __builtin_amdgcn_mfma_f32_16x16x32_bf16(ap[fm], aw[fc], acc[fm][fc], 0, 0, 0);
    }
#pragma unroll
    for (int fm = 0; fm < 4; ++fm)
#pragma unroll
        for (int fc = 0; fc < 4; ++fc)
#pragma unroll
            for (int r = 0; r < 4; ++r) {
                int m  = wid * 64 + fm * 16 + l4 * 4 + r;
                int co = fc * 16 + l15;
                float v = acc[fm][fc][r] + bias[co];
                v = v > 0.f ? v : 0.01f * v;
                y1[(((size_t)b * 20 + t) * 256 + m) * 64 + co] = f2bf(v);
            }
}

// ------- conv2: y1[b][t][256][64] -> y2[b][128][20][49] --------------------
__global__ __launch_bounds__(512, 2)
void conv2_kernel(const unsigned short* __restrict__ y1,
                  const unsigned short* __restrict__ w2,  // [128][3072]
                  const float* __restrict__ bias,
                  unsigned short* __restrict__ y2)
{
    const int b = blockIdx.x, t = blockIdx.y;
    const int tid = threadIdx.x, lane = tid & 63, wid = tid >> 6;
    const int wc = wid >> 1, wr = wid & 1;
    __shared__ unsigned short in_s[256 * 64];   // parity-cell layout, 32KB
    __shared__ unsigned short w_s[128 * 128];   // 128-k chunk, 32KB
    const int l15 = lane & 15, l4 = lane >> 4;

    const int m0v = wr * 32 + l15, m1v = m0v + 16;
    const int m0c = m0v < 49 ? m0v : 48, m1c = m1v < 49 ? m1v : 48;
    const int py0 = m0c / 7, px0 = m0c - py0 * 7;
    const int py1 = m1c / 7, px1 = m1c - py1 * 7;

    v4f acc[2][2];                              // [fc][fm]
#pragma unroll
    for (int i = 0; i < 2; ++i)
#pragma unroll
        for (int j = 0; j < 2; ++j) acc[i][j] = (v4f){0.f, 0.f, 0.f, 0.f};

    for (int dt = 0; dt < 3; ++dt) {
        int ts = t + dt - 1;
        __syncthreads();                        // in_s reuse guard
        if (ts < 0 || ts >= 20) continue;       // zero contribution (uniform)
#pragma unroll
        for (int p = 0; p < 4; ++p) {
            int idx = tid + p * 512;            // 2048 us8
            int slot = idx >> 3, c8 = idx & 7;
            int yy = slot >> 4, xx = slot & 15;
            us8 v = *reinterpret_cast<const us8*>(y1 + (((size_t)b * 20 + ts) * 256 + slot) * 64 + c8 * 8);
            int cell = ((yy & 1) * 2 + (xx & 1)) * 64 + (yy >> 1) * 8 + (xx >> 1);
            int byte = cell * 128 + ((c8 * 16) ^ (((cell ^ (cell >> 3)) & 7) << 4));
            *reinterpret_cast<us8*>(reinterpret_cast<char*>(in_s) + byte) = v;
        }
        for (int kc = 0; kc < 8; ++kc) {        // 8 x 128 k per dt
            __syncthreads();
#pragma unroll
            for (int p = 0; p < 4; ++p) {
                int idx = tid + p * 512;        // 2048 us8
                int co = idx >> 4, j = idx & 15;
                us8 v = *reinterpret_cast<const us8*>(w2 + (size_t)co * 3072 + dt * 1024 + kc * 128 + j * 8);
                *reinterpret_cast<us8*>(reinterpret_cast<char*>(w_s) + co * 256 + ((j * 16) ^ ((co & 7) << 4))) = v;
            }
            __syncthreads();
#pragma unroll
            for (int ks = 0; ks < 4; ++ks) {
                int klocal = ks * 32 + l4 * 8;
                int kk = kc * 128 + klocal;     // 0..1023 within dt
                int dy = (kk >> 8) & 3, dx = (kk >> 6) & 3, ci0 = kk & 63;
                v8bf aw[2], bp[2];
#pragma unroll
                for (int fc = 0; fc < 2; ++fc) {
                    int co = wc * 32 + fc * 16 + l15;
                    aw[fc] = *reinterpret_cast<const v8bf*>(reinterpret_cast<const char*>(w_s)
                               + co * 256 + ((klocal * 2) ^ ((co & 7) << 4)));
                }
                int plane = ((dy & 1) << 1) | (dx & 1);
                int c0 = plane * 64 + (py0 + (dy >> 1)) * 8 + px0 + (dx >> 1);
                int c1 = plane * 64 + (py1 + (dy >> 1)) * 8 + px1 + (dx >> 1);
                bp[0] = *reinterpret_cast<const v8bf*>(reinterpret_cast<const char*>(in_s)
                          + c0 * 128 + ((ci0 * 2) ^ (((c0 ^ (c0 >> 3)) & 7) << 4)));
                bp[1] = *reinterpret_cast<const v8bf*>(reinterpret_cast<const char*>(in_s)
                          + c1 * 128 + ((ci0 * 2) ^ (((c1 ^ (c1 >> 3)) & 7) << 4)));
#pragma unroll
                for (int fc = 0; fc < 2; ++fc)
#pragma unroll
                    for (int fm = 0; fm < 2; ++fm)
                        acc[fc][fm] = __builtin_amdgcn_mfma_f32_16x16x32_bf16(aw[fc], bp[fm], acc[fc][fm], 0, 0, 0);
            }
        }
    }
#pragma unroll
    for (int fc = 0; fc < 2; ++fc)
#pragma unroll
        for (int fm = 0; fm < 2; ++fm)
#pragma unroll
            for (int r = 0; r < 4; ++r) {
                int co = wc * 32 + fc * 16 + l4 * 4 + r;
                int m  = wr * 32 + fm * 16 + l15;
                if (m < 49) {
                    float v = acc[fc][fm][r] + bias[co];
                    v = v > 0.f ? v : 0.01f * v;
                    y2[(((size_t)b * 128 + co) * 20 + t) * 49 + m] = f2bf(v);
                }
            }
}

// ------- linear epilogue: sum 7 split-K parts, +bias, split mu/logvar ------
__global__ __launch_bounds__(256)
void lin_epi(const float* __restrict__ linC, const float* __restrict__ lb,
             float* __restrict__ out)
{
    int i = blockIdx.x * 256 + threadIdx.x;      // 0..327679
    int m = i >> 8, n = i & 255;
    float v = lb[n];
#pragma unroll
    for (int z = 0; z < 7; ++z) v += linC[(size_t)z * 327680 + i];
    size_t o = (n < 128) ? ((size_t)m * 128 + n) : (163840 + (size_t)m * 128 + (n - 128));
    out[o] = v;
}

extern "C" void kernel_launch(void* const* d_in, const int* in_sizes, int n_in,
                              void* d_out, int out_size, void* d_ws, size_t ws_size,
                              hipStream_t stream)
{
    const float* x   = (const float*)d_in[0];
    const float* Win = (const float*)d_in[1];
    const float* U   = (const float*)d_in[2];
    const float* Wr  = (const float*)d_in[3];
    const float* c1w = (const float*)d_in[4];
    const float* c1b = (const float*)d_in[5];
    const float* c2w = (const float*)d_in[6];
    const float* c2b = (const float*)d_in[7];
    const float* lw  = (const float*)d_in[8];
    const float* lb  = (const float*)d_in[9];

    char* ws = (char*)d_ws;
    unsigned short* WrTile = (unsigned short*)(ws);                 // 128 MB tiled
    unsigned short* xbf  = (unsigned short*)(ws);                   // 10.5 MB, dead before WrTile
    unsigned short* WT   = (unsigned short*)(ws + 134217728ll);     // 64 MB (WinTile then UT)
    float*          part16 = (float*)      (ws + 134217728ll);      // 16 MB scan部分 (UT dead, y1 later)
    unsigned short* y1   = (unsigned short*)(ws + 134217728ll);     // 41.9 MB (after scan)
    unsigned short* y2   = (unsigned short*)(ws + 176160768ll);     // 12.85 MB
    unsigned short* XALL = (unsigned short*)(ws + 201326592ll);     // 21 MB [20][64][8192]
    unsigned short* Hbf  = (unsigned short*)(ws + 222298112ll);     // 21 MB [b][t][1024][8]
    unsigned short* hb0  = (unsigned short*)(ws + 243269632ll);     // 1 MB
    unsigned short* hb1  = (unsigned short*)(ws + 244318208ll);     // 1 MB
    float*          part = (float*)        (ws + 245366784ll);      // 8.4 MB (h0)
    float*          linC = (float*)        (ws + 245366784ll);      // 9.2 MB (aliases part)
    unsigned short* w1bf = (unsigned short*)(ws + 254541824ll);     // 28 KB
    unsigned short* w2bf = (unsigned short*)(ws + 254570496ll);     // 768 KB
    unsigned int*   tick = (unsigned int*) (ws + 255356928ll);      // 512 B
    float*          out  = (float*)d_out;

    cvt_w1<<<56, 256, 0, stream>>>(c1w, w1bf, tick);
    cvt_w2<<<1536, 256, 0, stream>>>(c2w, w2bf);
    cvt_x<<<2560, 256, 0, stream>>>(x, xbf);

    // h0 = tanh(x0 @ Win): WinTile (tiled transpose) + KZ=4 pipelined step
    transpose_f32_bf16_tiled<<<dim3(128, 64), 256, 0, stream>>>(Win, WT, 8192, 64);
    scan_step<<<512, 256, 0, stream>>>(xbf, 81920, WT, 64, 1024,
                                       (const unsigned short*)nullptr, hb0, Hbf, 0, part, tick);

    // xU = x[:,1:] @ U  — reverted to nt-fastest grid (R8 behavior)
    transpose_f32_bf16<<<dim3(128, 64), 256, 0, stream>>>(U, WT, 4096, 8192);
    gemm_bt<128, true, true, false><<<dim3(64, 19, 1), 256, 0, stream>>>(
        x + 4096, 81920, 4096, WT, 4096, XALL + 524288, 8192, 4096, 0ll);

    // reservoir scan t=1..19: split-K 8, high-occupancy step (part16 in dead-UT region)
    transpose_f32_bf16_tiled<<<dim3(128, 128), 256, 0, stream>>>(Wr, WrTile, 8192, 128);
    for (int t = 1; t < 20; ++t) {
        const unsigned short* hprev = (t & 1) ? hb0 : hb1;
        unsigned short*       hnext = (t & 1) ? hb1 : hb0;
        scan_step2<<<1024, 256, 0, stream>>>(hprev, 8192, WrTile, 128, 1024,
                                             XALL + (size_t)t * 524288, hnext, Hbf, t, part16, tick);
    }

    conv1_kernel<<<dim3(64, 20), 256, 0, stream>>>(Hbf, w1bf, c1b, y1);
    conv2_kernel<<<dim3(64, 20), 512, 0, stream>>>(y1, w2bf, c2b, y2);

    // linear head: A = y2 as [1280][6272] bf16, BT = lin_w fp32, split-K 7
    gemm_bt<128, false, false, true><<<dim3(2, 20, 7), 256, 0, stream>>>(
        y2, 6272, 6272 * 64, lw, 6272, linC, 256, 896, 327680ll);
    lin_epi<<<1280, 256, 0, stream>>>(linC, lb, out);
}

// Round 12
// 1637.063 us; speedup vs baseline: 1.1064x; 1.1064x over previous
//
#include <hip/hip_runtime.h>

typedef __bf16 v8bf __attribute__((ext_vector_type(8)));
typedef float  v4f  __attribute__((ext_vector_type(4)));
typedef unsigned short us8 __attribute__((ext_vector_type(8)));

__device__ __forceinline__ float bf2f(unsigned short u) {
    union { unsigned int i; float f; } v; v.i = ((unsigned int)u) << 16; return v.f;
}
__device__ __forceinline__ unsigned short f2bf(float f) {
    union { float f; unsigned int i; } v; v.f = f;
    return (unsigned short)((v.i + 0x7fffu + ((v.i >> 16) & 1u)) >> 16);
}
// address involution swizzle: XOR 16B-slot bits (4-6) with bits 7-9. Bijective.
__device__ __forceinline__ int sw(int b) { return b ^ (((b >> 7) & 7) << 4); }

// ------- transpose+downcast (row-major out): dst[n][k] = bf16(src[k][n]) ----
__global__ __launch_bounds__(256)
void transpose_f32_bf16(const float* __restrict__ src,
                        unsigned short* __restrict__ dst, int K, int N)
{
    __shared__ unsigned short tile[64][72];
    const int tid = threadIdx.x;
    const int c0 = blockIdx.x * 64, r0 = blockIdx.y * 64;
    const int tr = tid >> 2, tc4 = tid & 3;
    const float* sp = src + (size_t)(r0 + tr) * N + c0 + tc4 * 16;
#pragma unroll
    for (int j = 0; j < 4; ++j) {
        v4f f = *reinterpret_cast<const v4f*>(sp + j * 4);
#pragma unroll
        for (int e = 0; e < 4; ++e) tile[tr][tc4 * 16 + j * 4 + e] = f2bf(f[e]);
    }
    __syncthreads();
    const int ow = tid >> 3, och = tid & 7;
#pragma unroll
    for (int p = 0; p < 2; ++p) {
        int orow = p * 32 + ow;
        us8 o;
#pragma unroll
        for (int e = 0; e < 8; ++e) o[e] = tile[och * 8 + e][orow];
        *reinterpret_cast<us8*>(dst + (size_t)(c0 + orow) * K + r0 + och * 8) = o;
    }
}

// ------- transpose+downcast (TILED out): tile (nt=bx, kt=by) is 8KB contig,
// slot pre-swizzled so scan stage() reads linearly & LDS-read swizzle works.
__global__ __launch_bounds__(256)
void transpose_f32_bf16_tiled(const float* __restrict__ src,
                              unsigned short* __restrict__ dst, int N, int ktiles)
{
    __shared__ unsigned short tile[64][72];
    const int tid = threadIdx.x;
    const int c0 = blockIdx.x * 64, r0 = blockIdx.y * 64;
    const int tr = tid >> 2, tc4 = tid & 3;
    const float* sp = src + (size_t)(r0 + tr) * N + c0 + tc4 * 16;
#pragma unroll
    for (int j = 0; j < 4; ++j) {
        v4f f = *reinterpret_cast<const v4f*>(sp + j * 4);
#pragma unroll
        for (int e = 0; e < 4; ++e) tile[tr][tc4 * 16 + j * 4 + e] = f2bf(f[e]);
    }
    __syncthreads();
    const int ow = tid >> 3, och = tid & 7;
    unsigned short* tb = dst + ((size_t)blockIdx.x * ktiles + blockIdx.y) * 4096;
#pragma unroll
    for (int p = 0; p < 2; ++p) {
        int orow = p * 32 + ow;                     // n-in-tile (row)
        us8 o;
#pragma unroll
        for (int e = 0; e < 8; ++e) o[e] = tile[och * 8 + e][orow];
        *reinterpret_cast<us8*>(tb + orow * 64 + (och ^ (orow & 7)) * 8) = o;
    }
}

// ------- x fp32 -> bf16 ----------------------------------------------------
__global__ __launch_bounds__(256)
void cvt_x(const float* __restrict__ x, unsigned short* __restrict__ xb)
{
    int i = blockIdx.x * 256 + threadIdx.x;      // 655360 groups of 8
    if (i >= 655360) return;
    v4f f0 = *reinterpret_cast<const v4f*>(x + (size_t)i * 8);
    v4f f1 = *reinterpret_cast<const v4f*>(x + (size_t)i * 8 + 4);
    us8 o;
#pragma unroll
    for (int e = 0; e < 4; ++e) { o[e] = f2bf(f0[e]); o[4 + e] = f2bf(f1[e]); }
    *reinterpret_cast<us8*>(xb + (size_t)i * 8) = o;
}

// ------- generic GEMM (xU / linear); B transposed (BT[n][k]) ---------------
template<int BN, bool STORE_BF16, bool AF32, bool BF32>
__global__ __launch_bounds__(256, 2)
void gemm_bt(const void* __restrict__ Ap, int lda_lo, int lda_hi,
             const void* __restrict__ BTp, int ldb,
             void* __restrict__ Cout, int ldc,
             int ksub, long long csplit_stride)
{
    constexpr int FN  = BN / 32;
    constexpr int BCH = BN / 32;
    const int tid = threadIdx.x;
    const int lane = tid & 63, wid = tid >> 6;
    const int wr = wid >> 1, wc = wid & 1;
    const int nt = blockIdx.x, mt = blockIdx.y, kz = blockIdx.z;
    const int n0 = nt * BN;
    const int kstart = kz * ksub;

    __shared__ unsigned short smem[(64 + BN) * 64];
    char* As = reinterpret_cast<char*>(smem);
    char* Bs = reinterpret_cast<char*>(smem + 64 * 64);

    const unsigned short* A16 = (const unsigned short*)Ap;
    const float*          A32 = (const float*)Ap;
    const unsigned short* B16 = (const unsigned short*)BTp;
    const float*          B32 = (const float*)BTp;

    const int arow = AF32 ? (tid >> 2) : (tid >> 3);
    const int aq   = AF32 ? (tid & 3) : (tid & 7);
    const float* Ab32 = A32 + (size_t)arow * lda_lo + (size_t)mt * lda_hi + kstart + aq * 16;
    const unsigned short* Ab16 = A16 + (size_t)arow * lda_lo + (size_t)mt * lda_hi + kstart + aq * 8;
    const int brow = tid >> 3, bq = tid & 7;
    const float* Bb32 = B32 + (size_t)(n0 + brow) * ldb + kstart + bq * 8;
    const unsigned short* Bb16 = B16 + (size_t)(n0 + brow) * ldb + kstart + bq * 8;

    v4f fa[4];
    us8 ra[2];
    v4f fb[BCH][2];
    us8 rb[BCH];

    auto load = [&](int kk) {
        if (AF32) {
#pragma unroll
            for (int j = 0; j < 4; ++j)
                fa[j] = *reinterpret_cast<const v4f*>(Ab32 + kk + j * 4);
        } else {
#pragma unroll
            for (int p = 0; p < 2; ++p)
                ra[p] = *reinterpret_cast<const us8*>(Ab16 + (size_t)(p * 32) * lda_lo + kk);
        }
        if (BF32) {
#pragma unroll
            for (int p = 0; p < BCH; ++p) {
                fb[p][0] = *reinterpret_cast<const v4f*>(Bb32 + (size_t)(p * 32) * ldb + kk);
                fb[p][1] = *reinterpret_cast<const v4f*>(Bb32 + (size_t)(p * 32) * ldb + kk + 4);
            }
        } else {
#pragma unroll
            for (int p = 0; p < BCH; ++p)
                rb[p] = *reinterpret_cast<const us8*>(Bb16 + (size_t)(p * 32) * ldb + kk);
        }
    };
    auto stage = [&]() {
        if (AF32) {
#pragma unroll
            for (int h = 0; h < 2; ++h) {
                us8 v;
#pragma unroll
                for (int e = 0; e < 8; ++e) v[e] = f2bf(fa[h * 2 + (e >> 2)][e & 3]);
                *reinterpret_cast<us8*>(As + arow * 128 + (((aq * 2 + h) * 16) ^ ((arow & 7) << 4))) = v;
            }
        } else {
#pragma unroll
            for (int p = 0; p < 2; ++p)
                *reinterpret_cast<us8*>(As + (arow + p * 32) * 128 + ((aq * 16) ^ ((arow & 7) << 4))) = ra[p];
        }
#pragma unroll
        for (int p = 0; p < BCH; ++p) {
            us8 v;
            if (BF32) {
#pragma unroll
                for (int e = 0; e < 8; ++e) v[e] = f2bf(fb[p][e >> 2][e & 3]);
            } else v = rb[p];
            *reinterpret_cast<us8*>(Bs + (brow + p * 32) * 128 + ((bq * 16) ^ ((brow & 7) << 4))) = v;
        }
    };

    v4f z4 = {0.f, 0.f, 0.f, 0.f};
    v4f acc[2][FN];
#pragma unroll
    for (int i = 0; i < 2; ++i)
#pragma unroll
        for (int j = 0; j < FN; ++j) acc[i][j] = z4;

    const int l15 = lane & 15, l4 = lane >> 4;
    const int nk = ksub / 64;
    load(0);
    for (int it = 0; it < nk; ++it) {
        __syncthreads();
        stage();
        __syncthreads();
        if (it + 1 < nk) load((it + 1) * 64);
#pragma unroll
        for (int ks = 0; ks < 2; ++ks) {
            const int kb = (ks * 32 + l4 * 8) * 2;
            v8bf af[2], bfr[FN];
#pragma unroll
            for (int fm = 0; fm < 2; ++fm) {
                int row = wr * 32 + fm * 16 + l15;
                af[fm] = *reinterpret_cast<const v8bf*>(As + row * 128 + (kb ^ ((row & 7) << 4)));
            }
#pragma unroll
            for (int fn = 0; fn < FN; ++fn) {
                int row = wc * (BN / 2) + fn * 16 + l15;
                bfr[fn] = *reinterpret_cast<const v8bf*>(Bs + row * 128 + (kb ^ ((row & 7) << 4)));
            }
#pragma unroll
            for (int fm = 0; fm < 2; ++fm)
#pragma unroll
                for (int fn = 0; fn < FN; ++fn)
                    acc[fm][fn] = __builtin_amdgcn_mfma_f32_16x16x32_bf16(af[fm], bfr[fn], acc[fm][fn], 0, 0, 0);
        }
    }
    const long long m0 = (long long)mt * 64;
#pragma unroll
    for (int fm = 0; fm < 2; ++fm)
#pragma unroll
        for (int fn = 0; fn < FN; ++fn)
#pragma unroll
            for (int r = 0; r < 4; ++r) {
                long long row = m0 + wr * 32 + fm * 16 + l4 * 4 + r;
                long long col = n0 + wc * (BN / 2) + fn * 16 + l15;
                long long idx = (long long)kz * csplit_stride + row * ldc + col;
                if (STORE_BF16) reinterpret_cast<unsigned short*>(Cout)[idx] = f2bf(acc[fm][fn][r]);
                else            reinterpret_cast<float*>(Cout)[idx]          = acc[fm][fn][r];
            }
}

// ------- h0 step: split-K 4, 4-buf counted-vmcnt pipeline (proven) ---------
#define KZ 4
__global__ __launch_bounds__(256, 2)
void scan_step(const unsigned short* __restrict__ A, int lda,
               const unsigned short* __restrict__ BTiles, int ktiles,
               int kper,
               const unsigned short* __restrict__ xu,
               unsigned short* __restrict__ hnext,
               unsigned short* __restrict__ Hbf, int t,
               float* __restrict__ part,
               unsigned int* __restrict__ tickets)
{
    const int tid = threadIdx.x, lane = tid & 63, wid = tid >> 6;
    const int wr = wid >> 1, wc = wid & 1;
    const int nt = blockIdx.x & 127, kz = blockIdx.x >> 7;
    const int n0 = nt * 64, kstart = kz * kper;
    const int l15 = lane & 15, l4 = lane >> 4;
    const int nit = kper >> 6;

    __shared__ unsigned short smem[32768];   // 64 KB: 4 bufs x (A 8KB + B 8KB)
    char* base = reinterpret_cast<char*>(smem);

    const int srow = tid >> 3, sq = tid & 7;
    const int gslot = sq ^ (srow & 7);
    const unsigned short* Asrc = A + (size_t)srow * lda + kstart + gslot * 8;
    const unsigned short* Bsrc = BTiles
        + ((size_t)(nt * ktiles + kz * (kper >> 6))) * 4096 + tid * 8;

    auto stage = [&](int buf, int it) {
        char* dA = base + buf * 16384 + wid * 1024;
        char* dB = dA + 8192;
        const int kk = it * 64;
#pragma unroll
        for (int p = 0; p < 2; ++p) {
            __builtin_amdgcn_global_load_lds(
                (const __attribute__((address_space(1))) void*)(Asrc + kk + (size_t)p * 32 * lda),
                (__attribute__((address_space(3))) void*)(dA + p * 4096), 16, 0, 0);
            __builtin_amdgcn_global_load_lds(
                (const __attribute__((address_space(1))) void*)(Bsrc + (size_t)it * 4096 + p * 2048),
                (__attribute__((address_space(3))) void*)(dB + p * 4096), 16, 0, 0);
        }
    };

    v4f acc00 = {0.f, 0.f, 0.f, 0.f};
    v4f acc01 = acc00, acc10 = acc00, acc11 = acc00;

    stage(0, 0); stage(1, 1); stage(2, 2);
    for (int it = 0; it < nit; ++it) {
        const int ahead = nit - 1 - it;
        if (ahead >= 2)      asm volatile("s_waitcnt vmcnt(8)" ::: "memory");
        else if (ahead == 1) asm volatile("s_waitcnt vmcnt(4)" ::: "memory");
        else                 asm volatile("s_waitcnt vmcnt(0)" ::: "memory");
        __builtin_amdgcn_s_barrier();
        __builtin_amdgcn_sched_barrier(0);
        if (it + 3 < nit) stage((it + 3) & 3, it + 3);
        const char* As = base + (it & 3) * 16384;
        const char* Bs = As + 8192;
#pragma unroll
        for (int ks = 0; ks < 2; ++ks) {
            const int kb = (ks * 32 + l4 * 8) * 2;
            v8bf a0, a1, b0, b1;
            { int row = wr * 32 + l15;      a0 = *reinterpret_cast<const v8bf*>(As + row * 128 + (kb ^ ((row & 7) << 4))); }
            { int row = wr * 32 + 16 + l15; a1 = *reinterpret_cast<const v8bf*>(As + row * 128 + (kb ^ ((row & 7) << 4))); }
            { int row = wc * 32 + l15;      b0 = *reinterpret_cast<const v8bf*>(Bs + row * 128 + (kb ^ ((row & 7) << 4))); }
            { int row = wc * 32 + 16 + l15; b1 = *reinterpret_cast<const v8bf*>(Bs + row * 128 + (kb ^ ((row & 7) << 4))); }
            acc00 = __builtin_amdgcn_mfma_f32_16x16x32_bf16(a0, b0, acc00, 0, 0, 0);
            acc01 = __builtin_amdgcn_mfma_f32_16x16x32_bf16(a0, b1, acc01, 0, 0, 0);
            acc10 = __builtin_amdgcn_mfma_f32_16x16x32_bf16(a1, b0, acc10, 0, 0, 0);
            acc11 = __builtin_amdgcn_mfma_f32_16x16x32_bf16(a1, b1, acc11, 0, 0, 0);
        }
    }

    float* mypart = part + (size_t)kz * 524288;
#pragma unroll
    for (int r = 0; r < 4; ++r) {
        int row0 = wr * 32 + l4 * 4 + r;
        int col0 = n0 + wc * 32 + l15;
        mypart[(size_t)row0 * 8192 + col0]             = acc00[r];
        mypart[(size_t)row0 * 8192 + col0 + 16]        = acc01[r];
        mypart[(size_t)(row0 + 16) * 8192 + col0]      = acc10[r];
        mypart[(size_t)(row0 + 16) * 8192 + col0 + 16] = acc11[r];
    }

    __shared__ int lastflag;
    __syncthreads();
    if (tid == 0) {
        unsigned int old = __hip_atomic_fetch_add(&tickets[nt], 1u,
                              __ATOMIC_ACQ_REL, __HIP_MEMORY_SCOPE_AGENT);
        lastflag = (old == KZ - 1);
    }
    __syncthreads();
    if (!lastflag) return;

    const int row = tid >> 2;
    const int c0 = n0 + (tid & 3) * 16;
    float pre[16];
    if (xu) {
        const us8* xp = reinterpret_cast<const us8*>(xu + (size_t)row * 8192 + c0);
        us8 x0 = xp[0], x1 = xp[1];
#pragma unroll
        for (int j = 0; j < 8; ++j) { pre[j] = bf2f(x0[j]); pre[8 + j] = bf2f(x1[j]); }
    } else {
#pragma unroll
        for (int j = 0; j < 16; ++j) pre[j] = 0.f;
    }
#pragma unroll
    for (int z = 0; z < KZ; ++z) {
        const float* pp = part + (size_t)z * 524288 + (size_t)row * 8192 + c0;
#pragma unroll
        for (int q = 0; q < 4; ++q) {
            v4f v = *reinterpret_cast<const v4f*>(pp + q * 4);
#pragma unroll
            for (int e = 0; e < 4; ++e) pre[q * 4 + e] += v[e];
        }
    }
    us8 o0, o1;
#pragma unroll
    for (int j = 0; j < 16; ++j) {
        unsigned short hb = f2bf(tanhf(pre[j]));
        if (j < 8) o0[j] = hb; else o1[j - 8] = hb;
        int col = c0 + j;
        Hbf[(((size_t)row * 20 + t) * 1024 + (col & 1023)) * 8 + (col >> 10)] = hb;
    }
    *reinterpret_cast<us8*>(hnext + (size_t)row * 8192 + c0)     = o0;
    *reinterpret_cast<us8*>(hnext + (size_t)row * 8192 + c0 + 8) = o1;
    if (tid == 0)
        __hip_atomic_store(&tickets[nt], 0u, __ATOMIC_RELAXED, __HIP_MEMORY_SCOPE_AGENT);
}

// ------- persistent scan t=1..19 with DATAFLOW sync (no grid barrier) ------
// 512 blocks = 128 nt x 4 kz, all co-resident (64KB LDS -> 2/CU).
// GEMM(nt,kz,t) waits ready[kz] >= 32*(t-1); combine(nt,t) releases ready[nt/32].
// Partials parity-double-buffered; tickets are per-step (no reset -> no race).
__global__ __launch_bounds__(256, 2)
void scan_persist2(const unsigned short* __restrict__ WrTiles,  // [128][128] 8KB tiles
                   const unsigned short* __restrict__ xall,     // [20][64][8192]
                   unsigned short* __restrict__ hb0,
                   unsigned short* __restrict__ hb1,
                   unsigned short* __restrict__ Hbf,
                   float* __restrict__ part2,                   // [2][4][64][8192]
                   unsigned int* __restrict__ tscan,            // [19*128]
                   unsigned int* __restrict__ ready)            // [128] (4 used, stride 32)
{
    const int tid = threadIdx.x, lane = tid & 63, wid = tid >> 6;
    const int wr = wid >> 1, wc = wid & 1;
    const int nt = blockIdx.x & 127, kz = blockIdx.x >> 7;
    const int n0 = nt * 64, kstart = kz * 2048;
    const int l15 = lane & 15, l4 = lane >> 4;

    __shared__ unsigned short smem[32768];   // 64 KB: 4 bufs x (A 8KB + B 8KB)
    char* base = reinterpret_cast<char*>(smem);

    const int srow = tid >> 3, sq = tid & 7;
    const int gslot = sq ^ (srow & 7);
    const unsigned short* Bsrc = WrTiles + ((size_t)(nt * 128 + kz * 32)) * 4096 + tid * 8;
    unsigned int* rdy = ready + kz * 32;            // my k-range gate
    unsigned int* rmy = ready + (nt >> 5) * 32;     // range my strip feeds

    for (int t = 1; t < 20; ++t) {
        const unsigned short* hprev = (t & 1) ? hb0 : hb1;
        unsigned short*       hnext = (t & 1) ? hb1 : hb0;

        if (t > 1) {
            if (tid == 0) {
                const unsigned int tgt = 32u * (unsigned)(t - 1);
                while (__hip_atomic_load(rdy, __ATOMIC_RELAXED, __HIP_MEMORY_SCOPE_AGENT) < tgt)
                    __builtin_amdgcn_s_sleep(2);
                (void)__hip_atomic_load(rdy, __ATOMIC_ACQUIRE, __HIP_MEMORY_SCOPE_AGENT);
            }
            __syncthreads();
        }

        const unsigned short* Asrc = hprev + (size_t)srow * 8192 + kstart + gslot * 8;
        auto stage = [&](int buf, int it) {
            char* dA = base + buf * 16384 + wid * 1024;
            char* dB = dA + 8192;
            const int kk = it * 64;
#pragma unroll
            for (int p = 0; p < 2; ++p) {
                __builtin_amdgcn_global_load_lds(
                    (const __attribute__((address_space(1))) void*)(Asrc + kk + (size_t)p * 32 * 8192),
                    (__attribute__((address_space(3))) void*)(dA + p * 4096), 16, 0, 0);
                __builtin_amdgcn_global_load_lds(
                    (const __attribute__((address_space(1))) void*)(Bsrc + (size_t)it * 4096 + p * 2048),
                    (__attribute__((address_space(3))) void*)(dB + p * 4096), 16, 0, 0);
            }
        };

        v4f acc00 = {0.f, 0.f, 0.f, 0.f};
        v4f acc01 = acc00, acc10 = acc00, acc11 = acc00;

        stage(0, 0); stage(1, 1); stage(2, 2);
        for (int it = 0; it < 32; ++it) {
            const int ahead = 31 - it;
            if (ahead >= 2)      asm volatile("s_waitcnt vmcnt(8)" ::: "memory");
            else if (ahead == 1) asm volatile("s_waitcnt vmcnt(4)" ::: "memory");
            else                 asm volatile("s_waitcnt vmcnt(0)" ::: "memory");
            __builtin_amdgcn_s_barrier();
            __builtin_amdgcn_sched_barrier(0);
            if (it + 3 < 32) stage((it + 3) & 3, it + 3);
            const char* As = base + (it & 3) * 16384;
            const char* Bs = As + 8192;
#pragma unroll
            for (int ks = 0; ks < 2; ++ks) {
                const int kb = (ks * 32 + l4 * 8) * 2;
                v8bf a0, a1, b0, b1;
                { int row = wr * 32 + l15;      a0 = *reinterpret_cast<const v8bf*>(As + row * 128 + (kb ^ ((row & 7) << 4))); }
                { int row = wr * 32 + 16 + l15; a1 = *reinterpret_cast<const v8bf*>(As + row * 128 + (kb ^ ((row & 7) << 4))); }
                { int row = wc * 32 + l15;      b0 = *reinterpret_cast<const v8bf*>(Bs + row * 128 + (kb ^ ((row & 7) << 4))); }
                { int row = wc * 32 + 16 + l15; b1 = *reinterpret_cast<const v8bf*>(Bs + row * 128 + (kb ^ ((row & 7) << 4))); }
                acc00 = __builtin_amdgcn_mfma_f32_16x16x32_bf16(a0, b0, acc00, 0, 0, 0);
                acc01 = __builtin_amdgcn_mfma_f32_16x16x32_bf16(a0, b1, acc01, 0, 0, 0);
                acc10 = __builtin_amdgcn_mfma_f32_16x16x32_bf16(a1, b0, acc10, 0, 0, 0);
                acc11 = __builtin_amdgcn_mfma_f32_16x16x32_bf16(a1, b1, acc11, 0, 0, 0);
            }
        }

        float* mypart = part2 + ((size_t)((t & 1) * 4 + kz)) * 524288;
#pragma unroll
        for (int r = 0; r < 4; ++r) {
            int row0 = wr * 32 + l4 * 4 + r;
            int col0 = n0 + wc * 32 + l15;
            mypart[(size_t)row0 * 8192 + col0]             = acc00[r];
            mypart[(size_t)row0 * 8192 + col0 + 16]        = acc01[r];
            mypart[(size_t)(row0 + 16) * 8192 + col0]      = acc10[r];
            mypart[(size_t)(row0 + 16) * 8192 + col0 + 16] = acc11[r];
        }

        __shared__ int lastflag;
        __syncthreads();
        if (tid == 0) {
            unsigned int old = __hip_atomic_fetch_add(&tscan[(t - 1) * 128 + nt], 1u,
                                  __ATOMIC_ACQ_REL, __HIP_MEMORY_SCOPE_AGENT);
            lastflag = (old == 3u);
        }
        __syncthreads();
        if (lastflag) {
            const int row = tid >> 2;
            const int c0 = n0 + (tid & 3) * 16;
            const unsigned short* xu = xall + (size_t)t * 524288;
            float pre[16];
            {
                const us8* xp = reinterpret_cast<const us8*>(xu + (size_t)row * 8192 + c0);
                us8 x0 = xp[0], x1 = xp[1];
#pragma unroll
                for (int j = 0; j < 8; ++j) { pre[j] = bf2f(x0[j]); pre[8 + j] = bf2f(x1[j]); }
            }
            const float* pbase = part2 + (size_t)(t & 1) * 4 * 524288;
#pragma unroll
            for (int z = 0; z < 4; ++z) {
                const float* pp = pbase + (size_t)z * 524288 + (size_t)row * 8192 + c0;
#pragma unroll
                for (int q = 0; q < 4; ++q) {
                    v4f v = *reinterpret_cast<const v4f*>(pp + q * 4);
#pragma unroll
                    for (int e = 0; e < 4; ++e) pre[q * 4 + e] += v[e];
                }
            }
            us8 o0, o1;
#pragma unroll
            for (int j = 0; j < 16; ++j) {
                unsigned short hb = f2bf(tanhf(pre[j]));
                if (j < 8) o0[j] = hb; else o1[j - 8] = hb;
                int col = c0 + j;
                Hbf[(((size_t)row * 20 + t) * 1024 + (col & 1023)) * 8 + (col >> 10)] = hb;
            }
            *reinterpret_cast<us8*>(hnext + (size_t)row * 8192 + c0)     = o0;
            *reinterpret_cast<us8*>(hnext + (size_t)row * 8192 + c0 + 8) = o1;
            __syncthreads();                    // all combine stores issued
            if (tid == 0)
                __hip_atomic_fetch_add(rmy, 1u, __ATOMIC_ACQ_REL, __HIP_MEMORY_SCOPE_AGENT);
        }
    }
}

// ------- weight conversion + sync-state reset ------------------------------
__global__ __launch_bounds__(256)
void cvt_w1(const float* __restrict__ w, unsigned short* __restrict__ o,
            unsigned int* __restrict__ tickets,
            unsigned int* __restrict__ tscan,
            unsigned int* __restrict__ ready)
{
    int gi = blockIdx.x * 256 + threadIdx.x;
    if (gi < 2432) tscan[gi] = 0;
    if (gi < 128)  { tickets[gi] = 0; ready[gi] = 0; }
    if (gi >= 64 * 224) return;
    int co = gi / 224, k = gi % 224;
    int g = k >> 3, ci = k & 7;
    float v = 0.f;
    if (g < 27) {
        int dt = g / 9, rr = g % 9, dy = rr / 3, dx = rr % 3;
        v = w[(((co * 8 + ci) * 3 + dt) * 3 + dy) * 3 + dx];
    }
    o[gi] = f2bf(v);
}
__global__ __launch_bounds__(256)
void cvt_w2(const float* __restrict__ w, unsigned short* __restrict__ o)
{
    int idx = blockIdx.x * 256 + threadIdx.x;    // 128*3072
    if (idx >= 128 * 3072) return;
    int co = idx / 3072, k = idx % 3072;
    int g = k >> 6, ci = k & 63;
    int dt = g >> 4, dy = (g >> 2) & 3, dx = g & 3;
    o[idx] = f2bf(w[(((co * 64 + ci) * 3 + dt) * 4 + dy) * 4 + dx]);
}

// ------- conv1: H[b][t][1024][8] -> y1[b][t][256][64] ----------------------
__global__ __launch_bounds__(256, 2)
void conv1_kernel(const unsigned short* __restrict__ H,
                  const unsigned short* __restrict__ w1,  // [64][224]
                  const float* __restrict__ bias,
                  unsigned short* __restrict__ y1)
{
    const int b = blockIdx.x, t = blockIdx.y;
    const int tid = threadIdx.x, lane = tid & 63, wid = tid >> 6;
    __shared__ unsigned short in_s[3 * 33 * 33 * 8];   // 52272 B
    __shared__ unsigned short w_s[64 * 224];           // stride 448 B

    for (int i = tid; i < 13068; i += 256) reinterpret_cast<unsigned int*>(in_s)[i] = 0;
    __syncthreads();
    for (int idx = tid; idx < 3 * 1024; idx += 256) {
        int dt = idx >> 10, rem = idx & 1023;
        int iy = rem >> 5, ix = rem & 31;
        int ts = t + dt - 1;
        if (ts >= 0 && ts < 20) {
            us8 v = *reinterpret_cast<const us8*>(H + (((size_t)b * 20 + ts) * 1024 + rem) * 8);
            int byte = ((dt * 33 + iy + 1) * 33 + (ix + 1)) * 16;
            *reinterpret_cast<us8*>(reinterpret_cast<char*>(in_s) + sw(byte)) = v;
        }
    }
    for (int idx = tid; idx < 64 * 28; idx += 256) {
        int co = idx / 28, j = idx % 28;
        us8 v = *reinterpret_cast<const us8*>(w1 + co * 224 + j * 8);
        *reinterpret_cast<us8*>(reinterpret_cast<char*>(w_s) + sw(co * 448 + j * 16)) = v;
    }
    __syncthreads();

    const int l15 = lane & 15, l4 = lane >> 4;
    const int m_lo = wid * 64 + l15;
    v4f z4 = {0.f, 0.f, 0.f, 0.f};
    v4f acc[4][4];                              // [fm][fc]
#pragma unroll
    for (int i = 0; i < 4; ++i)
#pragma unroll
        for (int j = 0; j < 4; ++j) acc[i][j] = z4;

#pragma unroll
    for (int ks = 0; ks < 7; ++ks) {
        int g = ks * 4 + l4;
        int gc = g < 27 ? g : 26;               // pad group: weights are zero
        int dt = gc / 9, rr = gc % 9, dy = rr / 3, dx = rr % 3;
        v8bf ap[4], aw[4];
#pragma unroll
        for (int fm = 0; fm < 4; ++fm) {
            int m = fm * 16 + m_lo;
            int py = m >> 4, px = m & 15;
            int byte = ((dt * 33 + 2 * py + dy) * 33 + 2 * px + dx) * 16;
            ap[fm] = *reinterpret_cast<const v8bf*>(reinterpret_cast<const char*>(in_s) + sw(byte));
        }
        int kb2 = (ks * 32 + l4 * 8) * 2;
#pragma unroll
        for (int fc = 0; fc < 4; ++fc) {
            int co = fc * 16 + l15;
            aw[fc] = *reinterpret_cast<const v8bf*>(reinterpret_cast<const char*>(w_s) + sw(co * 448 + kb2));
        }
#pragma unroll
        for (int fm = 0; fm < 4; ++fm)
#pragma unroll
            for (int fc = 0; fc < 4; ++fc)
                acc[fm][fc] = __builtin_amdgcn_mfma_f32_16x16x32_bf16(ap[fm], aw[fc], acc[fm][fc], 0, 0, 0);
    }
#pragma unroll
    for (int fm = 0; fm < 4; ++fm)
#pragma unroll
        for (int fc = 0; fc < 4; ++fc)
#pragma unroll
            for (int r = 0; r < 4; ++r) {
                int m  = wid * 64 + fm * 16 + l4 * 4 + r;
                int co = fc * 16 + l15;
                float v = acc[fm][fc][r] + bias[co];
                v = v > 0.f ? v : 0.01f * v;
                y1[(((size_t)b * 20 + t) * 256 + m) * 64 + co] = f2bf(v);
            }
}

// ------- conv2: y1[b][t][256][64] -> y2[b][128][20][49] --------------------
__global__ __launch_bounds__(512, 2)
void conv2_kernel(const unsigned short* __restrict__ y1,
                  const unsigned short* __restrict__ w2,  // [128][3072]
                  const float* __restrict__ bias,
                  unsigned short* __restrict__ y2)
{
    const int b = blockIdx.x, t = blockIdx.y;
    const int tid = threadIdx.x, lane = tid & 63, wid = tid >> 6;
    const int wc = wid >> 1, wr = wid & 1;
    __shared__ unsigned short in_s[256 * 64];   // parity-cell layout, 32KB
    __shared__ unsigned short w_s[128 * 128];   // 128-k chunk, 32KB
    const int l15 = lane & 15, l4 = lane >> 4;

    const int m0v = wr * 32 + l15, m1v = m0v + 16;
    const int m0c = m0v < 49 ? m0v : 48, m1c = m1v < 49 ? m1v : 48;
    const int py0 = m0c / 7, px0 = m0c - py0 * 7;
    const int py1 = m1c / 7, px1 = m1c - py1 * 7;

    v4f acc[2][2];                              // [fc][fm]
#pragma unroll
    for (int i = 0; i < 2; ++i)
#pragma unroll
        for (int j = 0; j < 2; ++j) acc[i][j] = (v4f){0.f, 0.f, 0.f, 0.f};

    for (int dt = 0; dt < 3; ++dt) {
        int ts = t + dt - 1;
        __syncthreads();                        // in_s reuse guard
        if (ts < 0 || ts >= 20) continue;       // zero contribution (uniform)
#pragma unroll
        for (int p = 0; p < 4; ++p) {
            int idx = tid + p * 512;            // 2048 us8
            int slot = idx >> 3, c8 = idx & 7;
            int yy = slot >> 4, xx = slot & 15;
            us8 v = *reinterpret_cast<const us8*>(y1 + (((size_t)b * 20 + ts) * 256 + slot) * 64 + c8 * 8);
            int cell = ((yy & 1) * 2 + (xx & 1)) * 64 + (yy >> 1) * 8 + (xx >> 1);
            int byte = cell * 128 + ((c8 * 16) ^ (((cell ^ (cell >> 3)) & 7) << 4));
            *reinterpret_cast<us8*>(reinterpret_cast<char*>(in_s) + byte) = v;
        }
        for (int kc = 0; kc < 8; ++kc) {        // 8 x 128 k per dt
            __syncthreads();
#pragma unroll
            for (int p = 0; p < 4; ++p) {
                int idx = tid + p * 512;        // 2048 us8
                int co = idx >> 4, j = idx & 15;
                us8 v = *reinterpret_cast<const us8*>(w2 + (size_t)co * 3072 + dt * 1024 + kc * 128 + j * 8);
                *reinterpret_cast<us8*>(reinterpret_cast<char*>(w_s) + co * 256 + ((j * 16) ^ ((co & 7) << 4))) = v;
            }
            __syncthreads();
#pragma unroll
            for (int ks = 0; ks < 4; ++ks) {
                int klocal = ks * 32 + l4 * 8;
                int kk = kc * 128 + klocal;     // 0..1023 within dt
                int dy = (kk >> 8) & 3, dx = (kk >> 6) & 3, ci0 = kk & 63;
                v8bf aw[2], bp[2];
#pragma unroll
                for (int fc = 0; fc < 2; ++fc) {
                    int co = wc * 32 + fc * 16 + l15;
                    aw[fc] = *reinterpret_cast<const v8bf*>(reinterpret_cast<const char*>(w_s)
                               + co * 256 + ((klocal * 2) ^ ((co & 7) << 4)));
                }
                int plane = ((dy & 1) << 1) | (dx & 1);
                int c0 = plane * 64 + (py0 + (dy >> 1)) * 8 + px0 + (dx >> 1);
                int c1 = plane * 64 + (py1 + (dy >> 1)) * 8 + px1 + (dx >> 1);
                bp[0] = *reinterpret_cast<const v8bf*>(reinterpret_cast<const char*>(in_s)
                          + c0 * 128 + ((ci0 * 2) ^ (((c0 ^ (c0 >> 3)) & 7) << 4)));
                bp[1] = *reinterpret_cast<const v8bf*>(reinterpret_cast<const char*>(in_s)
                          + c1 * 128 + ((ci0 * 2) ^ (((c1 ^ (c1 >> 3)) & 7) << 4)));
#pragma unroll
                for (int fc = 0; fc < 2; ++fc)
#pragma unroll
                    for (int fm = 0; fm < 2; ++fm)
                        acc[fc][fm] = __builtin_amdgcn_mfma_f32_16x16x32_bf16(aw[fc], bp[fm], acc[fc][fm], 0, 0, 0);
            }
        }
    }
#pragma unroll
    for (int fc = 0; fc < 2; ++fc)
#pragma unroll
        for (int fm = 0; fm < 2; ++fm)
#pragma unroll
            for (int r = 0; r < 4; ++r) {
                int co = wc * 32 + fc * 16 + l4 * 4 + r;
                int m  = wr * 32 + fm * 16 + l15;
                if (m < 49) {
                    float v = acc[fc][fm][r] + bias[co];
                    v = v > 0.f ? v : 0.01f * v;
                    y2[(((size_t)b * 128 + co) * 20 + t) * 49 + m] = f2bf(v);
                }
            }
}

// ------- linear epilogue: sum 7 split-K parts, +bias, split mu/logvar ------
__global__ __launch_bounds__(256)
void lin_epi(const float* __restrict__ linC, const float* __restrict__ lb,
             float* __restrict__ out)
{
    int i = blockIdx.x * 256 + threadIdx.x;      // 0..327679
    int m = i >> 8, n = i & 255;
    float v = lb[n];
#pragma unroll
    for (int z = 0; z < 7; ++z) v += linC[(size_t)z * 327680 + i];
    size_t o = (n < 128) ? ((size_t)m * 128 + n) : (163840 + (size_t)m * 128 + (n - 128));
    out[o] = v;
}

extern "C" void kernel_launch(void* const* d_in, const int* in_sizes, int n_in,
                              void* d_out, int out_size, void* d_ws, size_t ws_size,
                              hipStream_t stream)
{
    const float* x   = (const float*)d_in[0];
    const float* Win = (const float*)d_in[1];
    const float* U   = (const float*)d_in[2];
    const float* Wr  = (const float*)d_in[3];
    const float* c1w = (const float*)d_in[4];
    const float* c1b = (const float*)d_in[5];
    const float* c2w = (const float*)d_in[6];
    const float* c2b = (const float*)d_in[7];
    const float* lw  = (const float*)d_in[8];
    const float* lb  = (const float*)d_in[9];

    char* ws = (char*)d_ws;
    unsigned short* WrTile = (unsigned short*)(ws);                 // 128 MB tiled
    unsigned short* xbf  = (unsigned short*)(ws);                   // 10.5 MB, dead before WrTile
    unsigned short* WT   = (unsigned short*)(ws + 134217728ll);     // 64 MB (WinTile then UT)
    float*          part2 = (float*)       (ws + 134217728ll);      // 16.8 MB (scan; UT dead, y1 later)
    unsigned short* y1   = (unsigned short*)(ws + 134217728ll);     // 41.9 MB (after scan)
    unsigned short* y2   = (unsigned short*)(ws + 176160768ll);     // 12.85 MB
    unsigned short* XALL = (unsigned short*)(ws + 201326592ll);     // 21 MB [20][64][8192]
    unsigned short* Hbf  = (unsigned short*)(ws + 222298112ll);     // 21 MB [b][t][1024][8]
    unsigned short* hb0  = (unsigned short*)(ws + 243269632ll);     // 1 MB
    unsigned short* hb1  = (unsigned short*)(ws + 244318208ll);     // 1 MB
    float*          part = (float*)        (ws + 245366784ll);      // 8.4 MB (h0)
    float*          linC = (float*)        (ws + 245366784ll);      // 9.2 MB (aliases part)
    unsigned short* w1bf = (unsigned short*)(ws + 254541824ll);     // 28 KB
    unsigned short* w2bf = (unsigned short*)(ws + 254570496ll);     // 768 KB
    unsigned int*   tick = (unsigned int*) (ws + 255356928ll);      // 512 B
    unsigned int*   tscan= (unsigned int*) (ws + 255357440ll);      // 9.7 KB (19*128)
    unsigned int*   ready= (unsigned int*) (ws + 255367168ll);      // 512 B
    float*          out  = (float*)d_out;

    cvt_w1<<<56, 256, 0, stream>>>(c1w, w1bf, tick, tscan, ready);
    cvt_w2<<<1536, 256, 0, stream>>>(c2w, w2bf);
    cvt_x<<<2560, 256, 0, stream>>>(x, xbf);

    // h0 = tanh(x0 @ Win): WinTile (tiled transpose) + KZ=4 pipelined step
    transpose_f32_bf16_tiled<<<dim3(128, 64), 256, 0, stream>>>(Win, WT, 8192, 64);
    scan_step<<<512, 256, 0, stream>>>(xbf, 81920, WT, 64, 1024,
                                       (const unsigned short*)nullptr, hb0, Hbf, 0, part, tick);

    // xU = x[:,1:] @ U  — nt-fastest grid (R8/R6 behavior)
    transpose_f32_bf16<<<dim3(128, 64), 256, 0, stream>>>(U, WT, 4096, 8192);
    gemm_bt<128, true, true, false><<<dim3(64, 19, 1), 256, 0, stream>>>(
        x + 4096, 81920, 4096, WT, 4096, XALL + 524288, 8192, 4096, 0ll);

    // reservoir scan t=1..19: ONE persistent dispatch, dataflow-synced
    transpose_f32_bf16_tiled<<<dim3(128, 128), 256, 0, stream>>>(Wr, WrTile, 8192, 128);
    scan_persist2<<<512, 256, 0, stream>>>(WrTile, XALL, hb0, hb1, Hbf, part2, tscan, ready);

    conv1_kernel<<<dim3(64, 20), 256, 0, stream>>>(Hbf, w1bf, c1b, y1);
    conv2_kernel<<<dim3(64, 20), 512, 0, stream>>>(y1, w2bf, c2b, y2);

    // linear head: A = y2 as [1280][6272] bf16, BT = lin_w fp32, split-K 7
    gemm_bt<128, false, false, true><<<dim3(2, 20, 7), 256, 0, stream>>>(
        y2, 6272, 6272 * 64, lw, 6272, linC, 256, 896, 327680ll);
    lin_epi<<<1280, 256, 0, stream>>>(linC, lb, out);
}

// Round 13
// 1631.197 us; speedup vs baseline: 1.1104x; 1.0036x over previous
//
#include <hip/hip_runtime.h>

typedef __bf16 v8bf __attribute__((ext_vector_type(8)));
typedef float  v4f  __attribute__((ext_vector_type(4)));
typedef unsigned short us8 __attribute__((ext_vector_type(8)));

__device__ __forceinline__ float bf2f(unsigned short u) {
    union { unsigned int i; float f; } v; v.i = ((unsigned int)u) << 16; return v.f;
}
__device__ __forceinline__ unsigned short f2bf(float f) {
    union { float f; unsigned int i; } v; v.f = f;
    return (unsigned short)((v.i + 0x7fffu + ((v.i >> 16) & 1u)) >> 16);
}
// address involution swizzle: XOR 16B-slot bits (4-6) with bits 7-9. Bijective.
__device__ __forceinline__ int sw(int b) { return b ^ (((b >> 7) & 7) << 4); }

// ------- transpose+downcast (row-major out): dst[n][k] = bf16(src[k][n]) ----
__global__ __launch_bounds__(256)
void transpose_f32_bf16(const float* __restrict__ src,
                        unsigned short* __restrict__ dst, int K, int N)
{
    __shared__ unsigned short tile[64][72];
    const int tid = threadIdx.x;
    const int c0 = blockIdx.x * 64, r0 = blockIdx.y * 64;
    const int tr = tid >> 2, tc4 = tid & 3;
    const float* sp = src + (size_t)(r0 + tr) * N + c0 + tc4 * 16;
#pragma unroll
    for (int j = 0; j < 4; ++j) {
        v4f f = *reinterpret_cast<const v4f*>(sp + j * 4);
#pragma unroll
        for (int e = 0; e < 4; ++e) tile[tr][tc4 * 16 + j * 4 + e] = f2bf(f[e]);
    }
    __syncthreads();
    const int ow = tid >> 3, och = tid & 7;
#pragma unroll
    for (int p = 0; p < 2; ++p) {
        int orow = p * 32 + ow;
        us8 o;
#pragma unroll
        for (int e = 0; e < 8; ++e) o[e] = tile[och * 8 + e][orow];
        *reinterpret_cast<us8*>(dst + (size_t)(c0 + orow) * K + r0 + och * 8) = o;
    }
}

// ------- transpose+downcast (TILED out): tile (nt=bx, kt=by) is 8KB contig,
// slot pre-swizzled so scan stage() reads linearly & LDS-read swizzle works.
__global__ __launch_bounds__(256)
void transpose_f32_bf16_tiled(const float* __restrict__ src,
                              unsigned short* __restrict__ dst, int N, int ktiles)
{
    __shared__ unsigned short tile[64][72];
    const int tid = threadIdx.x;
    const int c0 = blockIdx.x * 64, r0 = blockIdx.y * 64;
    const int tr = tid >> 2, tc4 = tid & 3;
    const float* sp = src + (size_t)(r0 + tr) * N + c0 + tc4 * 16;
#pragma unroll
    for (int j = 0; j < 4; ++j) {
        v4f f = *reinterpret_cast<const v4f*>(sp + j * 4);
#pragma unroll
        for (int e = 0; e < 4; ++e) tile[tr][tc4 * 16 + j * 4 + e] = f2bf(f[e]);
    }
    __syncthreads();
    const int ow = tid >> 3, och = tid & 7;
    unsigned short* tb = dst + ((size_t)blockIdx.x * ktiles + blockIdx.y) * 4096;
#pragma unroll
    for (int p = 0; p < 2; ++p) {
        int orow = p * 32 + ow;                     // n-in-tile (row)
        us8 o;
#pragma unroll
        for (int e = 0; e < 8; ++e) o[e] = tile[och * 8 + e][orow];
        *reinterpret_cast<us8*>(tb + orow * 64 + (och ^ (orow & 7)) * 8) = o;
    }
}

// ------- x fp32 -> bf16 ----------------------------------------------------
__global__ __launch_bounds__(256)
void cvt_x(const float* __restrict__ x, unsigned short* __restrict__ xb)
{
    int i = blockIdx.x * 256 + threadIdx.x;      // 655360 groups of 8
    if (i >= 655360) return;
    v4f f0 = *reinterpret_cast<const v4f*>(x + (size_t)i * 8);
    v4f f1 = *reinterpret_cast<const v4f*>(x + (size_t)i * 8 + 4);
    us8 o;
#pragma unroll
    for (int e = 0; e < 4; ++e) { o[e] = f2bf(f0[e]); o[4 + e] = f2bf(f1[e]); }
    *reinterpret_cast<us8*>(xb + (size_t)i * 8) = o;
}

// ------- generic GEMM (linear head); B transposed (BT[n][k]) ---------------
template<int BN, bool STORE_BF16, bool AF32, bool BF32>
__global__ __launch_bounds__(256, 2)
void gemm_bt(const void* __restrict__ Ap, int lda_lo, int lda_hi,
             const void* __restrict__ BTp, int ldb,
             void* __restrict__ Cout, int ldc,
             int ksub, long long csplit_stride)
{
    constexpr int FN  = BN / 32;
    constexpr int BCH = BN / 32;
    const int tid = threadIdx.x;
    const int lane = tid & 63, wid = tid >> 6;
    const int wr = wid >> 1, wc = wid & 1;
    const int nt = blockIdx.x, mt = blockIdx.y, kz = blockIdx.z;
    const int n0 = nt * BN;
    const int kstart = kz * ksub;

    __shared__ unsigned short smem[(64 + BN) * 64];
    char* As = reinterpret_cast<char*>(smem);
    char* Bs = reinterpret_cast<char*>(smem + 64 * 64);

    const unsigned short* A16 = (const unsigned short*)Ap;
    const float*          A32 = (const float*)Ap;
    const unsigned short* B16 = (const unsigned short*)BTp;
    const float*          B32 = (const float*)BTp;

    const int arow = AF32 ? (tid >> 2) : (tid >> 3);
    const int aq   = AF32 ? (tid & 3) : (tid & 7);
    const float* Ab32 = A32 + (size_t)arow * lda_lo + (size_t)mt * lda_hi + kstart + aq * 16;
    const unsigned short* Ab16 = A16 + (size_t)arow * lda_lo + (size_t)mt * lda_hi + kstart + aq * 8;
    const int brow = tid >> 3, bq = tid & 7;
    const float* Bb32 = B32 + (size_t)(n0 + brow) * ldb + kstart + bq * 8;
    const unsigned short* Bb16 = B16 + (size_t)(n0 + brow) * ldb + kstart + bq * 8;

    v4f fa[4];
    us8 ra[2];
    v4f fb[BCH][2];
    us8 rb[BCH];

    auto load = [&](int kk) {
        if (AF32) {
#pragma unroll
            for (int j = 0; j < 4; ++j)
                fa[j] = *reinterpret_cast<const v4f*>(Ab32 + kk + j * 4);
        } else {
#pragma unroll
            for (int p = 0; p < 2; ++p)
                ra[p] = *reinterpret_cast<const us8*>(Ab16 + (size_t)(p * 32) * lda_lo + kk);
        }
        if (BF32) {
#pragma unroll
            for (int p = 0; p < BCH; ++p) {
                fb[p][0] = *reinterpret_cast<const v4f*>(Bb32 + (size_t)(p * 32) * ldb + kk);
                fb[p][1] = *reinterpret_cast<const v4f*>(Bb32 + (size_t)(p * 32) * ldb + kk + 4);
            }
        } else {
#pragma unroll
            for (int p = 0; p < BCH; ++p)
                rb[p] = *reinterpret_cast<const us8*>(Bb16 + (size_t)(p * 32) * ldb + kk);
        }
    };
    auto stage = [&]() {
        if (AF32) {
#pragma unroll
            for (int h = 0; h < 2; ++h) {
                us8 v;
#pragma unroll
                for (int e = 0; e < 8; ++e) v[e] = f2bf(fa[h * 2 + (e >> 2)][e & 3]);
                *reinterpret_cast<us8*>(As + arow * 128 + (((aq * 2 + h) * 16) ^ ((arow & 7) << 4))) = v;
            }
        } else {
#pragma unroll
            for (int p = 0; p < 2; ++p)
                *reinterpret_cast<us8*>(As + (arow + p * 32) * 128 + ((aq * 16) ^ ((arow & 7) << 4))) = ra[p];
        }
#pragma unroll
        for (int p = 0; p < BCH; ++p) {
            us8 v;
            if (BF32) {
#pragma unroll
                for (int e = 0; e < 8; ++e) v[e] = f2bf(fb[p][e >> 2][e & 3]);
            } else v = rb[p];
            *reinterpret_cast<us8*>(Bs + (brow + p * 32) * 128 + ((bq * 16) ^ ((brow & 7) << 4))) = v;
        }
    };

    v4f z4 = {0.f, 0.f, 0.f, 0.f};
    v4f acc[2][FN];
#pragma unroll
    for (int i = 0; i < 2; ++i)
#pragma unroll
        for (int j = 0; j < FN; ++j) acc[i][j] = z4;

    const int l15 = lane & 15, l4 = lane >> 4;
    const int nk = ksub / 64;
    load(0);
    for (int it = 0; it < nk; ++it) {
        __syncthreads();
        stage();
        __syncthreads();
        if (it + 1 < nk) load((it + 1) * 64);
#pragma unroll
        for (int ks = 0; ks < 2; ++ks) {
            const int kb = (ks * 32 + l4 * 8) * 2;
            v8bf af[2], bfr[FN];
#pragma unroll
            for (int fm = 0; fm < 2; ++fm) {
                int row = wr * 32 + fm * 16 + l15;
                af[fm] = *reinterpret_cast<const v8bf*>(As + row * 128 + (kb ^ ((row & 7) << 4)));
            }
#pragma unroll
            for (int fn = 0; fn < FN; ++fn) {
                int row = wc * (BN / 2) + fn * 16 + l15;
                bfr[fn] = *reinterpret_cast<const v8bf*>(Bs + row * 128 + (kb ^ ((row & 7) << 4)));
            }
#pragma unroll
            for (int fm = 0; fm < 2; ++fm)
#pragma unroll
                for (int fn = 0; fn < FN; ++fn)
                    acc[fm][fn] = __builtin_amdgcn_mfma_f32_16x16x32_bf16(af[fm], bfr[fn], acc[fm][fn], 0, 0, 0);
        }
    }
    const long long m0 = (long long)mt * 64;
#pragma unroll
    for (int fm = 0; fm < 2; ++fm)
#pragma unroll
        for (int fn = 0; fn < FN; ++fn)
#pragma unroll
            for (int r = 0; r < 4; ++r) {
                long long row = m0 + wr * 32 + fm * 16 + l4 * 4 + r;
                long long col = n0 + wc * (BN / 2) + fn * 16 + l15;
                long long idx = (long long)kz * csplit_stride + row * ldc + col;
                if (STORE_BF16) reinterpret_cast<unsigned short*>(Cout)[idx] = f2bf(acc[fm][fn][r]);
                else            reinterpret_cast<float*>(Cout)[idx]          = acc[fm][fn][r];
            }
}

// ------- xU GEMM: BM=128 (2 t-slots/block), BN=128, K=4096 -----------------
// A = xbf[b][t][4096] bf16; B = UT[n][k]; C = XALL[t][b][8192], t=1..19
__global__ __launch_bounds__(256, 2)
void gemm_xu(const unsigned short* __restrict__ xbf,
             const unsigned short* __restrict__ UT,
             unsigned short* __restrict__ XALL)
{
    const int tid = threadIdx.x, lane = tid & 63, wid = tid >> 6;
    const int wr = wid >> 1, wc = wid & 1;
    const int nt = blockIdx.x, mt = blockIdx.y;      // nt<64, mt<10
    const int n0 = nt * 128;
    const int l15 = lane & 15, l4 = lane >> 4;

    __shared__ unsigned short As[8192];   // 128 x 64, swizzled
    __shared__ unsigned short Bs[8192];

    const int arow = tid >> 1, aseg = tid & 1;       // row 0..127, 32-k segment
    {   // nothing
    }
    int tg = 1 + mt * 2 + (arow >> 6);
    if (tg > 19) tg = 19;                            // tail clamp (store skipped)
    const unsigned short* Abase = xbf + (size_t)(arow & 63) * 81920 + (size_t)tg * 4096 + aseg * 32;
    const unsigned short* Bbase = UT + (size_t)(n0 + arow) * 4096 + aseg * 32;

    us8 ra[4], rb[4];
    auto load = [&](int kk) {
#pragma unroll
        for (int j = 0; j < 4; ++j) {
            ra[j] = *reinterpret_cast<const us8*>(Abase + kk + j * 8);
            rb[j] = *reinterpret_cast<const us8*>(Bbase + kk + j * 8);
        }
    };
    auto stage = [&]() {
#pragma unroll
        for (int j = 0; j < 4; ++j) {
            int byte = ((aseg * 4 + j) * 16) ^ ((arow & 7) << 4);
            *reinterpret_cast<us8*>(reinterpret_cast<char*>(As) + arow * 128 + byte) = ra[j];
            *reinterpret_cast<us8*>(reinterpret_cast<char*>(Bs) + arow * 128 + byte) = rb[j];
        }
    };

    v4f acc[4][4];
#pragma unroll
    for (int i = 0; i < 4; ++i)
#pragma unroll
        for (int j = 0; j < 4; ++j) acc[i][j] = (v4f){0.f, 0.f, 0.f, 0.f};

    load(0);
    for (int it = 0; it < 64; ++it) {
        __syncthreads();
        stage();
        __syncthreads();
        if (it + 1 < 64) load((it + 1) * 64);
#pragma unroll
        for (int ks = 0; ks < 2; ++ks) {
            const int kb = (ks * 32 + l4 * 8) * 2;
            v8bf af[4], bfr[4];
#pragma unroll
            for (int f = 0; f < 4; ++f) {
                int rowA = wr * 64 + f * 16 + l15;
                af[f] = *reinterpret_cast<const v8bf*>(reinterpret_cast<const char*>(As)
                          + rowA * 128 + (kb ^ ((rowA & 7) << 4)));
                int rowB = wc * 64 + f * 16 + l15;
                bfr[f] = *reinterpret_cast<const v8bf*>(reinterpret_cast<const char*>(Bs)
                          + rowB * 128 + (kb ^ ((rowB & 7) << 4)));
            }
#pragma unroll
            for (int fm = 0; fm < 4; ++fm)
#pragma unroll
                for (int fn = 0; fn < 4; ++fn)
                    acc[fm][fn] = __builtin_amdgcn_mfma_f32_16x16x32_bf16(af[fm], bfr[fn], acc[fm][fn], 0, 0, 0);
        }
    }
    const int tg2 = 1 + mt * 2 + wr;
    if (tg2 <= 19) {
        unsigned short* Cb = XALL + (size_t)tg2 * 524288;
#pragma unroll
        for (int fm = 0; fm < 4; ++fm)
#pragma unroll
            for (int fn = 0; fn < 4; ++fn)
#pragma unroll
                for (int r = 0; r < 4; ++r) {
                    int b = fm * 16 + l4 * 4 + r;
                    int col = n0 + wc * 64 + fn * 16 + l15;
                    Cb[(size_t)b * 8192 + col] = f2bf(acc[fm][fn][r]);
                }
    }
}

// ------- reservoir step (also h0): split-K 4 + fused last-block combine ----
// R6-proven 2-buf syncthreads pipeline; tiled B; NT hints on streaming traffic.
#define KZ 4
__global__ __launch_bounds__(256, 2)
void scan_step(const unsigned short* __restrict__ A, int lda,
               const unsigned short* __restrict__ BTiles, int ktiles,
               int kper,
               const unsigned short* __restrict__ xu,
               unsigned short* __restrict__ hnext,
               unsigned short* __restrict__ Hbf, int t,
               float* __restrict__ part,
               unsigned int* __restrict__ tickets)
{
    const int tid = threadIdx.x, lane = tid & 63, wid = tid >> 6;
    const int wr = wid >> 1, wc = wid & 1;
    const int nt = blockIdx.x & 127, kz = blockIdx.x >> 7;
    const int n0 = nt * 64, kstart = kz * kper;
    const int l15 = lane & 15, l4 = lane >> 4;
    const int nit = kper >> 6;

    __shared__ unsigned short smem[16384];   // 32 KB: 2 bufs x (A 8KB + B 8KB)
    char* base = reinterpret_cast<char*>(smem);

    const int srow = tid >> 3, sq = tid & 7;
    const int gslot = sq ^ (srow & 7);
    const unsigned short* Asrc = A + (size_t)srow * lda + kstart + gslot * 8;
    const unsigned short* Bsrc = BTiles
        + ((size_t)(nt * ktiles + kz * (kper >> 6))) * 4096 + tid * 8;

    auto stage = [&](int buf, int it) {
        char* dA = base + buf * 16384 + wid * 1024;
        char* dB = dA + 8192;
        const int kk = it * 64;
#pragma unroll
        for (int p = 0; p < 2; ++p) {
            __builtin_amdgcn_global_load_lds(
                (const __attribute__((address_space(1))) void*)(Asrc + kk + (size_t)p * 32 * lda),
                (__attribute__((address_space(3))) void*)(dA + p * 4096), 16, 0, 0);
            __builtin_amdgcn_global_load_lds(
                (const __attribute__((address_space(1))) void*)(Bsrc + (size_t)it * 4096 + p * 2048),
                (__attribute__((address_space(3))) void*)(dB + p * 4096), 16, 0, 0);
        }
    };

    v4f acc00 = {0.f, 0.f, 0.f, 0.f};
    v4f acc01 = acc00, acc10 = acc00, acc11 = acc00;

    stage(0, 0);
    for (int it = 0; it < nit; ++it) {
        const int cur = it & 1;
        __syncthreads();                             // stage(cur) landed; cur^1 free
        if (it + 1 < nit) stage(cur ^ 1, it + 1);
        const char* As = base + cur * 16384;
        const char* Bs = As + 8192;
#pragma unroll
        for (int ks = 0; ks < 2; ++ks) {
            const int kb = (ks * 32 + l4 * 8) * 2;
            v8bf a0, a1, b0, b1;
            { int row = wr * 32 + l15;      a0 = *reinterpret_cast<const v8bf*>(As + row * 128 + (kb ^ ((row & 7) << 4))); }
            { int row = wr * 32 + 16 + l15; a1 = *reinterpret_cast<const v8bf*>(As + row * 128 + (kb ^ ((row & 7) << 4))); }
            { int row = wc * 32 + l15;      b0 = *reinterpret_cast<const v8bf*>(Bs + row * 128 + (kb ^ ((row & 7) << 4))); }
            { int row = wc * 32 + 16 + l15; b1 = *reinterpret_cast<const v8bf*>(Bs + row * 128 + (kb ^ ((row & 7) << 4))); }
            acc00 = __builtin_amdgcn_mfma_f32_16x16x32_bf16(a0, b0, acc00, 0, 0, 0);
            acc01 = __builtin_amdgcn_mfma_f32_16x16x32_bf16(a0, b1, acc01, 0, 0, 0);
            acc10 = __builtin_amdgcn_mfma_f32_16x16x32_bf16(a1, b0, acc10, 0, 0, 0);
            acc11 = __builtin_amdgcn_mfma_f32_16x16x32_bf16(a1, b1, acc11, 0, 0, 0);
        }
    }

    // partial store (non-temporal: single-use, keep out of L3 so Wr stays hot)
    float* mypart = part + (size_t)kz * 524288;
#pragma unroll
    for (int r = 0; r < 4; ++r) {
        int row0 = wr * 32 + l4 * 4 + r;
        int col0 = n0 + wc * 32 + l15;
        __builtin_nontemporal_store(acc00[r], &mypart[(size_t)row0 * 8192 + col0]);
        __builtin_nontemporal_store(acc01[r], &mypart[(size_t)row0 * 8192 + col0 + 16]);
        __builtin_nontemporal_store(acc10[r], &mypart[(size_t)(row0 + 16) * 8192 + col0]);
        __builtin_nontemporal_store(acc11[r], &mypart[(size_t)(row0 + 16) * 8192 + col0 + 16]);
    }

    __shared__ int lastflag;
    __syncthreads();
    if (tid == 0) {
        unsigned int old = __hip_atomic_fetch_add(&tickets[nt], 1u,
                              __ATOMIC_ACQ_REL, __HIP_MEMORY_SCOPE_AGENT);
        lastflag = (old == KZ - 1);
    }
    __syncthreads();
    if (!lastflag) return;

    const int row = tid >> 2;
    const int c0 = n0 + (tid & 3) * 16;
    float pre[16];
    if (xu) {
        const us8* xp = reinterpret_cast<const us8*>(xu + (size_t)row * 8192 + c0);
        us8 x0 = __builtin_nontemporal_load(xp);
        us8 x1 = __builtin_nontemporal_load(xp + 1);
#pragma unroll
        for (int j = 0; j < 8; ++j) { pre[j] = bf2f(x0[j]); pre[8 + j] = bf2f(x1[j]); }
    } else {
#pragma unroll
        for (int j = 0; j < 16; ++j) pre[j] = 0.f;
    }
#pragma unroll
    for (int z = 0; z < KZ; ++z) {
        const float* pp = part + (size_t)z * 524288 + (size_t)row * 8192 + c0;
#pragma unroll
        for (int q = 0; q < 4; ++q) {
            v4f v = __builtin_nontemporal_load(reinterpret_cast<const v4f*>(pp + q * 4));
#pragma unroll
            for (int e = 0; e < 4; ++e) pre[q * 4 + e] += v[e];
        }
    }
    us8 o0, o1;
#pragma unroll
    for (int j = 0; j < 16; ++j) {
        unsigned short hb = f2bf(tanhf(pre[j]));
        if (j < 8) o0[j] = hb; else o1[j - 8] = hb;
        int col = c0 + j;
        __builtin_nontemporal_store(hb,
            &Hbf[(((size_t)row * 20 + t) * 1024 + (col & 1023)) * 8 + (col >> 10)]);
    }
    *reinterpret_cast<us8*>(hnext + (size_t)row * 8192 + c0)     = o0;  // hot next step
    *reinterpret_cast<us8*>(hnext + (size_t)row * 8192 + c0 + 8) = o1;
    if (tid == 0)
        __hip_atomic_store(&tickets[nt], 0u, __ATOMIC_RELAXED, __HIP_MEMORY_SCOPE_AGENT);
}

// ------- weight conversion to GEMM k-order bf16 ----------------------------
__global__ __launch_bounds__(256)
void cvt_w1(const float* __restrict__ w, unsigned short* __restrict__ o,
            unsigned int* __restrict__ tickets)
{
    if (blockIdx.x == 0 && threadIdx.x < 128) tickets[threadIdx.x] = 0;
    int idx = blockIdx.x * 256 + threadIdx.x;    // 64*224
    if (idx >= 64 * 224) return;
    int co = idx / 224, k = idx % 224;
    int g = k >> 3, ci = k & 7;
    float v = 0.f;
    if (g < 27) {
        int dt = g / 9, rr = g % 9, dy = rr / 3, dx = rr % 3;
        v = w[(((co * 8 + ci) * 3 + dt) * 3 + dy) * 3 + dx];
    }
    o[idx] = f2bf(v);
}
__global__ __launch_bounds__(256)
void cvt_w2(const float* __restrict__ w, unsigned short* __restrict__ o)
{
    int idx = blockIdx.x * 256 + threadIdx.x;    // 128*3072
    if (idx >= 128 * 3072) return;
    int co = idx / 3072, k = idx % 3072;
    int g = k >> 6, ci = k & 63;
    int dt = g >> 4, dy = (g >> 2) & 3, dx = g & 3;
    o[idx] = f2bf(w[(((co * 64 + ci) * 3 + dt) * 4 + dy) * 4 + dx]);
}

// ------- conv1: H[b][t][1024][8] -> y1[b][t][256][64] ----------------------
__global__ __launch_bounds__(256, 2)
void conv1_kernel(const unsigned short* __restrict__ H,
                  const unsigned short* __restrict__ w1,  // [64][224]
                  const float* __restrict__ bias,
                  unsigned short* __restrict__ y1)
{
    const int b = blockIdx.x, t = blockIdx.y;
    const int tid = threadIdx.x, lane = tid & 63, wid = tid >> 6;
    __shared__ unsigned short in_s[3 * 33 * 33 * 8];   // 52272 B
    __shared__ unsigned short w_s[64 * 224];           // stride 448 B

    for (int i = tid; i < 13068; i += 256) reinterpret_cast<unsigned int*>(in_s)[i] = 0;
    __syncthreads();
    for (int idx = tid; idx < 3 * 1024; idx += 256) {
        int dt = idx >> 10, rem = idx & 1023;
        int iy = rem >> 5, ix = rem & 31;
        int ts = t + dt - 1;
        if (ts >= 0 && ts < 20) {
            us8 v = *reinterpret_cast<const us8*>(H + (((size_t)b * 20 + ts) * 1024 + rem) * 8);
            int byte = ((dt * 33 + iy + 1) * 33 + (ix + 1)) * 16;
            *reinterpret_cast<us8*>(reinterpret_cast<char*>(in_s) + sw(byte)) = v;
        }
    }
    for (int idx = tid; idx < 64 * 28; idx += 256) {
        int co = idx / 28, j = idx % 28;
        us8 v = *reinterpret_cast<const us8*>(w1 + co * 224 + j * 8);
        *reinterpret_cast<us8*>(reinterpret_cast<char*>(w_s) + sw(co * 448 + j * 16)) = v;
    }
    __syncthreads();

    const int l15 = lane & 15, l4 = lane >> 4;
    const int m_lo = wid * 64 + l15;
    v4f z4 = {0.f, 0.f, 0.f, 0.f};
    v4f acc[4][4];                              // [fm][fc]
#pragma unroll
    for (int i = 0; i < 4; ++i)
#pragma unroll
        for (int j = 0; j < 4; ++j) acc[i][j] = z4;

#pragma unroll
    for (int ks = 0; ks < 7; ++ks) {
        int g = ks * 4 + l4;
        int gc = g < 27 ? g : 26;               // pad group: weights are zero
        int dt = gc / 9, rr = gc % 9, dy = rr / 3, dx = rr % 3;
        v8bf ap[4], aw[4];
#pragma unroll
        for (int fm = 0; fm < 4; ++fm) {
            int m = fm * 16 + m_lo;
            int py = m >> 4, px = m & 15;
            int byte = ((dt * 33 + 2 * py + dy) * 33 + 2 * px + dx) * 16;
            ap[fm] = *reinterpret_cast<const v8bf*>(reinterpret_cast<const char*>(in_s) + sw(byte));
        }
        int kb2 = (ks * 32 + l4 * 8) * 2;
#pragma unroll
        for (int fc = 0; fc < 4; ++fc) {
            int co = fc * 16 + l15;
            aw[fc] = *reinterpret_cast<const v8bf*>(reinterpret_cast<const char*>(w_s) + sw(co * 448 + kb2));
        }
#pragma unroll
        for (int fm = 0; fm < 4; ++fm)
#pragma unroll
            for (int fc = 0; fc < 4; ++fc)
                acc[fm][fc] = __builtin_amdgcn_mfma_f32_16x16x32_bf16(ap[fm], aw[fc], acc[fm][fc], 0, 0, 0);
    }
#pragma unroll
    for (int fm = 0; fm < 4; ++fm)
#pragma unroll
        for (int fc = 0; fc < 4; ++fc)
#pragma unroll
            for (int r = 0; r < 4; ++r) {
                int m  = wid * 64 + fm * 16 + l4 * 4 + r;
                int co = fc * 16 + l15;
                float v = acc[fm][fc][r] + bias[co];
                v = v > 0.f ? v : 0.01f * v;
                y1[(((size_t)b * 20 + t) * 256 + m) * 64 + co] = f2bf(v);
            }
}

// ------- conv2: y1[b][t][256][64] -> y2[b][128][20][49] --------------------
__global__ __launch_bounds__(512, 2)
void conv2_kernel(const unsigned short* __restrict__ y1,
                  const unsigned short* __restrict__ w2,  // [128][3072]
                  const float* __restrict__ bias,
                  unsigned short* __restrict__ y2)
{
    const int b = blockIdx.x, t = blockIdx.y;
    const int tid = threadIdx.x, lane = tid & 63, wid = tid >> 6;
    const int wc = wid >> 1, wr = wid & 1;
    __shared__ unsigned short in_s[256 * 64];   // parity-cell layout, 32KB
    __shared__ unsigned short w_s[128 * 128];   // 128-k chunk, 32KB
    const int l15 = lane & 15, l4 = lane >> 4;

    const int m0v = wr * 32 + l15, m1v = m0v + 16;
    const int m0c = m0v < 49 ? m0v : 48, m1c = m1v < 49 ? m1v : 48;
    const int py0 = m0c / 7, px0 = m0c - py0 * 7;
    const int py1 = m1c / 7, px1 = m1c - py1 * 7;

    v4f acc[2][2];                              // [fc][fm]
#pragma unroll
    for (int i = 0; i < 2; ++i)
#pragma unroll
        for (int j = 0; j < 2; ++j) acc[i][j] = (v4f){0.f, 0.f, 0.f, 0.f};

    for (int dt = 0; dt < 3; ++dt) {
        int ts = t + dt - 1;
        __syncthreads();                        // in_s reuse guard
        if (ts < 0 || ts >= 20) continue;       // zero contribution (uniform)
#pragma unroll
        for (int p = 0; p < 4; ++p) {
            int idx = tid + p * 512;            // 2048 us8
            int slot = idx >> 3, c8 = idx & 7;
            int yy = slot >> 4, xx = slot & 15;
            us8 v = *reinterpret_cast<const us8*>(y1 + (((size_t)b * 20 + ts) * 256 + slot) * 64 + c8 * 8);
            int cell = ((yy & 1) * 2 + (xx & 1)) * 64 + (yy >> 1) * 8 + (xx >> 1);
            int byte = cell * 128 + ((c8 * 16) ^ (((cell ^ (cell >> 3)) & 7) << 4));
            *reinterpret_cast<us8*>(reinterpret_cast<char*>(in_s) + byte) = v;
        }
        for (int kc = 0; kc < 8; ++kc) {        // 8 x 128 k per dt
            __syncthreads();
#pragma unroll
            for (int p = 0; p < 4; ++p) {
                int idx = tid + p * 512;        // 2048 us8
                int co = idx >> 4, j = idx & 15;
                us8 v = *reinterpret_cast<const us8*>(w2 + (size_t)co * 3072 + dt * 1024 + kc * 128 + j * 8);
                *reinterpret_cast<us8*>(reinterpret_cast<char*>(w_s) + co * 256 + ((j * 16) ^ ((co & 7) << 4))) = v;
            }
            __syncthreads();
#pragma unroll
            for (int ks = 0; ks < 4; ++ks) {
                int klocal = ks * 32 + l4 * 8;
                int kk = kc * 128 + klocal;     // 0..1023 within dt
                int dy = (kk >> 8) & 3, dx = (kk >> 6) & 3, ci0 = kk & 63;
                v8bf aw[2], bp[2];
#pragma unroll
                for (int fc = 0; fc < 2; ++fc) {
                    int co = wc * 32 + fc * 16 + l15;
                    aw[fc] = *reinterpret_cast<const v8bf*>(reinterpret_cast<const char*>(w_s)
                               + co * 256 + ((klocal * 2) ^ ((co & 7) << 4)));
                }
                int plane = ((dy & 1) << 1) | (dx & 1);
                int c0 = plane * 64 + (py0 + (dy >> 1)) * 8 + px0 + (dx >> 1);
                int c1 = plane * 64 + (py1 + (dy >> 1)) * 8 + px1 + (dx >> 1);
                bp[0] = *reinterpret_cast<const v8bf*>(reinterpret_cast<const char*>(in_s)
                          + c0 * 128 + ((ci0 * 2) ^ (((c0 ^ (c0 >> 3)) & 7) << 4)));
                bp[1] = *reinterpret_cast<const v8bf*>(reinterpret_cast<const char*>(in_s)
                          + c1 * 128 + ((ci0 * 2) ^ (((c1 ^ (c1 >> 3)) & 7) << 4)));
#pragma unroll
                for (int fc = 0; fc < 2; ++fc)
#pragma unroll
                    for (int fm = 0; fm < 2; ++fm)
                        acc[fc][fm] = __builtin_amdgcn_mfma_f32_16x16x32_bf16(aw[fc], bp[fm], acc[fc][fm], 0, 0, 0);
            }
        }
    }
#pragma unroll
    for (int fc = 0; fc < 2; ++fc)
#pragma unroll
        for (int fm = 0; fm < 2; ++fm)
#pragma unroll
            for (int r = 0; r < 4; ++r) {
                int co = wc * 32 + fc * 16 + l4 * 4 + r;
                int m  = wr * 32 + fm * 16 + l15;
                if (m < 49) {
                    float v = acc[fc][fm][r] + bias[co];
                    v = v > 0.f ? v : 0.01f * v;
                    y2[(((size_t)b * 128 + co) * 20 + t) * 49 + m] = f2bf(v);
                }
            }
}

// ------- linear epilogue: sum 7 split-K parts, +bias, split mu/logvar ------
__global__ __launch_bounds__(256)
void lin_epi(const float* __restrict__ linC, const float* __restrict__ lb,
             float* __restrict__ out)
{
    int i = blockIdx.x * 256 + threadIdx.x;      // 0..327679
    int m = i >> 8, n = i & 255;
    float v = lb[n];
#pragma unroll
    for (int z = 0; z < 7; ++z) v += linC[(size_t)z * 327680 + i];
    size_t o = (n < 128) ? ((size_t)m * 128 + n) : (163840 + (size_t)m * 128 + (n - 128));
    out[o] = v;
}

extern "C" void kernel_launch(void* const* d_in, const int* in_sizes, int n_in,
                              void* d_out, int out_size, void* d_ws, size_t ws_size,
                              hipStream_t stream)
{
    const float* x   = (const float*)d_in[0];
    const float* Win = (const float*)d_in[1];
    const float* U   = (const float*)d_in[2];
    const float* Wr  = (const float*)d_in[3];
    const float* c1w = (const float*)d_in[4];
    const float* c1b = (const float*)d_in[5];
    const float* c2w = (const float*)d_in[6];
    const float* c2b = (const float*)d_in[7];
    const float* lw  = (const float*)d_in[8];
    const float* lb  = (const float*)d_in[9];

    char* ws = (char*)d_ws;
    unsigned short* WrTile = (unsigned short*)(ws);                 // 128 MB tiled
    unsigned short* xbf  = (unsigned short*)(ws);                   // 10.5 MB, dead before WrTile
    unsigned short* WT   = (unsigned short*)(ws + 134217728ll);     // 64 MB (WinTile then UT)
    unsigned short* y1   = (unsigned short*)(ws + 134217728ll);     // 41.9 MB (after xU)
    unsigned short* y2   = (unsigned short*)(ws + 176160768ll);     // 16.1 MB
    unsigned short* XALL = (unsigned short*)(ws + 201326592ll);     // 21 MB [20][64][8192]
    unsigned short* Hbf  = (unsigned short*)(ws + 222298112ll);     // 21 MB [b][t][1024][8]
    unsigned short* hb0  = (unsigned short*)(ws + 243269632ll);     // 1 MB
    unsigned short* hb1  = (unsigned short*)(ws + 244318208ll);     // 1 MB
    float*          part = (float*)        (ws + 245366784ll);      // 8.4 MB (h0 + scan)
    float*          linC = (float*)        (ws + 245366784ll);      // 9.2 MB (aliases part)
    unsigned short* w1bf = (unsigned short*)(ws + 254541824ll);     // 28 KB
    unsigned short* w2bf = (unsigned short*)(ws + 254570496ll);     // 768 KB
    unsigned int*   tick = (unsigned int*) (ws + 255356928ll);      // 512 B
    float*          out  = (float*)d_out;

    cvt_w1<<<56, 256, 0, stream>>>(c1w, w1bf, tick);
    cvt_w2<<<1536, 256, 0, stream>>>(c2w, w2bf);
    cvt_x<<<2560, 256, 0, stream>>>(x, xbf);

    // h0 = tanh(x0 @ Win): WinTile (tiled transpose) + KZ=4 pipelined step
    transpose_f32_bf16_tiled<<<dim3(128, 64), 256, 0, stream>>>(Win, WT, 8192, 64);
    scan_step<<<512, 256, 0, stream>>>(xbf, 81920, WT, 64, 1024,
                                       (const unsigned short*)nullptr, hb0, Hbf, 0, part, tick);

    // xU = x[:,1:] @ U  — BM=128 (2 t/block) halves UT re-streams
    transpose_f32_bf16<<<dim3(128, 64), 256, 0, stream>>>(U, WT, 4096, 8192);
    gemm_xu<<<dim3(64, 10), 256, 0, stream>>>(xbf, WT, XALL);

    // reservoir scan t=1..19: per-step fused split-K kernel, tiled Wr + NT hints
    transpose_f32_bf16_tiled<<<dim3(128, 128), 256, 0, stream>>>(Wr, WrTile, 8192, 128);
    for (int t = 1; t < 20; ++t) {
        const unsigned short* hprev = (t & 1) ? hb0 : hb1;
        unsigned short*       hnext = (t & 1) ? hb1 : hb0;
        scan_step<<<512, 256, 0, stream>>>(hprev, 8192, WrTile, 128, 2048,
                                           XALL + (size_t)t * 524288, hnext, Hbf, t, part, tick);
    }

    conv1_kernel<<<dim3(64, 20), 256, 0, stream>>>(Hbf, w1bf, c1b, y1);
    conv2_kernel<<<dim3(64, 20), 512, 0, stream>>>(y1, w2bf, c2b, y2);

    // linear head: A = y2 as [1280][6272] bf16, BT = lin_w fp32, split-K 7
    gemm_bt<128, false, false, true><<<dim3(2, 20, 7), 256, 0, stream>>>(
        y2, 6272, 6272 * 64, lw, 6272, linC, 256, 896, 327680ll);
    lin_epi<<<1280, 256, 0, stream>>>(linC, lb, out);
}

// Round 14
// 1620.747 us; speedup vs baseline: 1.1175x; 1.0064x over previous
//
#include <hip/hip_runtime.h>

typedef __bf16 v8bf __attribute__((ext_vector_type(8)));
typedef float  v4f  __attribute__((ext_vector_type(4)));
typedef unsigned short us8 __attribute__((ext_vector_type(8)));

__device__ __forceinline__ float bf2f(unsigned short u) {
    union { unsigned int i; float f; } v; v.i = ((unsigned int)u) << 16; return v.f;
}
__device__ __forceinline__ unsigned short f2bf(float f) {
    union { float f; unsigned int i; } v; v.f = f;
    return (unsigned short)((v.i + 0x7fffu + ((v.i >> 16) & 1u)) >> 16);
}
// address involution swizzle: XOR 16B-slot bits (4-6) with bits 7-9. Bijective.
__device__ __forceinline__ int sw(int b) { return b ^ (((b >> 7) & 7) << 4); }

// ------- transpose+downcast (row-major out): dst[n][k] = bf16(src[k][n]) ----
__global__ __launch_bounds__(256)
void transpose_f32_bf16(const float* __restrict__ src,
                        unsigned short* __restrict__ dst, int K, int N)
{
    __shared__ unsigned short tile[64][72];
    const int tid = threadIdx.x;
    const int c0 = blockIdx.x * 64, r0 = blockIdx.y * 64;
    const int tr = tid >> 2, tc4 = tid & 3;
    const float* sp = src + (size_t)(r0 + tr) * N + c0 + tc4 * 16;
#pragma unroll
    for (int j = 0; j < 4; ++j) {
        v4f f = *reinterpret_cast<const v4f*>(sp + j * 4);
#pragma unroll
        for (int e = 0; e < 4; ++e) tile[tr][tc4 * 16 + j * 4 + e] = f2bf(f[e]);
    }
    __syncthreads();
    const int ow = tid >> 3, och = tid & 7;
#pragma unroll
    for (int p = 0; p < 2; ++p) {
        int orow = p * 32 + ow;
        us8 o;
#pragma unroll
        for (int e = 0; e < 8; ++e) o[e] = tile[och * 8 + e][orow];
        *reinterpret_cast<us8*>(dst + (size_t)(c0 + orow) * K + r0 + och * 8) = o;
    }
}

// ------- transpose+downcast (TILED out): tile (nt=bx, kt=by) is 8KB contig,
// slot pre-swizzled so scan stage() reads linearly & LDS-read swizzle works.
__global__ __launch_bounds__(256)
void transpose_f32_bf16_tiled(const float* __restrict__ src,
                              unsigned short* __restrict__ dst, int N, int ktiles)
{
    __shared__ unsigned short tile[64][72];
    const int tid = threadIdx.x;
    const int c0 = blockIdx.x * 64, r0 = blockIdx.y * 64;
    const int tr = tid >> 2, tc4 = tid & 3;
    const float* sp = src + (size_t)(r0 + tr) * N + c0 + tc4 * 16;
#pragma unroll
    for (int j = 0; j < 4; ++j) {
        v4f f = *reinterpret_cast<const v4f*>(sp + j * 4);
#pragma unroll
        for (int e = 0; e < 4; ++e) tile[tr][tc4 * 16 + j * 4 + e] = f2bf(f[e]);
    }
    __syncthreads();
    const int ow = tid >> 3, och = tid & 7;
    unsigned short* tb = dst + ((size_t)blockIdx.x * ktiles + blockIdx.y) * 4096;
#pragma unroll
    for (int p = 0; p < 2; ++p) {
        int orow = p * 32 + ow;                     // n-in-tile (row)
        us8 o;
#pragma unroll
        for (int e = 0; e < 8; ++e) o[e] = tile[och * 8 + e][orow];
        *reinterpret_cast<us8*>(tb + orow * 64 + (och ^ (orow & 7)) * 8) = o;
    }
}

// ------- x fp32 -> bf16 ----------------------------------------------------
__global__ __launch_bounds__(256)
void cvt_x(const float* __restrict__ x, unsigned short* __restrict__ xb)
{
    int i = blockIdx.x * 256 + threadIdx.x;      // 655360 groups of 8
    if (i >= 655360) return;
    v4f f0 = *reinterpret_cast<const v4f*>(x + (size_t)i * 8);
    v4f f1 = *reinterpret_cast<const v4f*>(x + (size_t)i * 8 + 4);
    us8 o;
#pragma unroll
    for (int e = 0; e < 4; ++e) { o[e] = f2bf(f0[e]); o[4 + e] = f2bf(f1[e]); }
    *reinterpret_cast<us8*>(xb + (size_t)i * 8) = o;
}

// ------- generic GEMM (linear head); B transposed (BT[n][k]) ---------------
template<int BN, bool STORE_BF16, bool AF32, bool BF32>
__global__ __launch_bounds__(256, 2)
void gemm_bt(const void* __restrict__ Ap, int lda_lo, int lda_hi,
             const void* __restrict__ BTp, int ldb,
             void* __restrict__ Cout, int ldc,
             int ksub, long long csplit_stride)
{
    constexpr int FN  = BN / 32;
    constexpr int BCH = BN / 32;
    const int tid = threadIdx.x;
    const int lane = tid & 63, wid = tid >> 6;
    const int wr = wid >> 1, wc = wid & 1;
    const int nt = blockIdx.x, mt = blockIdx.y, kz = blockIdx.z;
    const int n0 = nt * BN;
    const int kstart = kz * ksub;

    __shared__ unsigned short smem[(64 + BN) * 64];
    char* As = reinterpret_cast<char*>(smem);
    char* Bs = reinterpret_cast<char*>(smem + 64 * 64);

    const unsigned short* A16 = (const unsigned short*)Ap;
    const float*          A32 = (const float*)Ap;
    const unsigned short* B16 = (const unsigned short*)BTp;
    const float*          B32 = (const float*)BTp;

    const int arow = AF32 ? (tid >> 2) : (tid >> 3);
    const int aq   = AF32 ? (tid & 3) : (tid & 7);
    const float* Ab32 = A32 + (size_t)arow * lda_lo + (size_t)mt * lda_hi + kstart + aq * 16;
    const unsigned short* Ab16 = A16 + (size_t)arow * lda_lo + (size_t)mt * lda_hi + kstart + aq * 8;
    const int brow = tid >> 3, bq = tid & 7;
    const float* Bb32 = B32 + (size_t)(n0 + brow) * ldb + kstart + bq * 8;
    const unsigned short* Bb16 = B16 + (size_t)(n0 + brow) * ldb + kstart + bq * 8;

    v4f fa[4];
    us8 ra[2];
    v4f fb[BCH][2];
    us8 rb[BCH];

    auto load = [&](int kk) {
        if (AF32) {
#pragma unroll
            for (int j = 0; j < 4; ++j)
                fa[j] = *reinterpret_cast<const v4f*>(Ab32 + kk + j * 4);
        } else {
#pragma unroll
            for (int p = 0; p < 2; ++p)
                ra[p] = *reinterpret_cast<const us8*>(Ab16 + (size_t)(p * 32) * lda_lo + kk);
        }
        if (BF32) {
#pragma unroll
            for (int p = 0; p < BCH; ++p) {
                fb[p][0] = *reinterpret_cast<const v4f*>(Bb32 + (size_t)(p * 32) * ldb + kk);
                fb[p][1] = *reinterpret_cast<const v4f*>(Bb32 + (size_t)(p * 32) * ldb + kk + 4);
            }
        } else {
#pragma unroll
            for (int p = 0; p < BCH; ++p)
                rb[p] = *reinterpret_cast<const us8*>(Bb16 + (size_t)(p * 32) * ldb + kk);
        }
    };
    auto stage = [&]() {
        if (AF32) {
#pragma unroll
            for (int h = 0; h < 2; ++h) {
                us8 v;
#pragma unroll
                for (int e = 0; e < 8; ++e) v[e] = f2bf(fa[h * 2 + (e >> 2)][e & 3]);
                *reinterpret_cast<us8*>(As + arow * 128 + (((aq * 2 + h) * 16) ^ ((arow & 7) << 4))) = v;
            }
        } else {
#pragma unroll
            for (int p = 0; p < 2; ++p)
                *reinterpret_cast<us8*>(As + (arow + p * 32) * 128 + ((aq * 16) ^ ((arow & 7) << 4))) = ra[p];
        }
#pragma unroll
        for (int p = 0; p < BCH; ++p) {
            us8 v;
            if (BF32) {
#pragma unroll
                for (int e = 0; e < 8; ++e) v[e] = f2bf(fb[p][e >> 2][e & 3]);
            } else v = rb[p];
            *reinterpret_cast<us8*>(Bs + (brow + p * 32) * 128 + ((bq * 16) ^ ((brow & 7) << 4))) = v;
        }
    };

    v4f z4 = {0.f, 0.f, 0.f, 0.f};
    v4f acc[2][FN];
#pragma unroll
    for (int i = 0; i < 2; ++i)
#pragma unroll
        for (int j = 0; j < FN; ++j) acc[i][j] = z4;

    const int l15 = lane & 15, l4 = lane >> 4;
    const int nk = ksub / 64;
    load(0);
    for (int it = 0; it < nk; ++it) {
        __syncthreads();
        stage();
        __syncthreads();
        if (it + 1 < nk) load((it + 1) * 64);
#pragma unroll
        for (int ks = 0; ks < 2; ++ks) {
            const int kb = (ks * 32 + l4 * 8) * 2;
            v8bf af[2], bfr[FN];
#pragma unroll
            for (int fm = 0; fm < 2; ++fm) {
                int row = wr * 32 + fm * 16 + l15;
                af[fm] = *reinterpret_cast<const v8bf*>(As + row * 128 + (kb ^ ((row & 7) << 4)));
            }
#pragma unroll
            for (int fn = 0; fn < FN; ++fn) {
                int row = wc * (BN / 2) + fn * 16 + l15;
                bfr[fn] = *reinterpret_cast<const v8bf*>(Bs + row * 128 + (kb ^ ((row & 7) << 4)));
            }
#pragma unroll
            for (int fm = 0; fm < 2; ++fm)
#pragma unroll
                for (int fn = 0; fn < FN; ++fn)
                    acc[fm][fn] = __builtin_amdgcn_mfma_f32_16x16x32_bf16(af[fm], bfr[fn], acc[fm][fn], 0, 0, 0);
        }
    }
    const long long m0 = (long long)mt * 64;
#pragma unroll
    for (int fm = 0; fm < 2; ++fm)
#pragma unroll
        for (int fn = 0; fn < FN; ++fn)
#pragma unroll
            for (int r = 0; r < 4; ++r) {
                long long row = m0 + wr * 32 + fm * 16 + l4 * 4 + r;
                long long col = n0 + wc * (BN / 2) + fn * 16 + l15;
                long long idx = (long long)kz * csplit_stride + row * ldc + col;
                if (STORE_BF16) reinterpret_cast<unsigned short*>(Cout)[idx] = f2bf(acc[fm][fn][r]);
                else            reinterpret_cast<float*>(Cout)[idx]          = acc[fm][fn][r];
            }
}

// ------- xU GEMM: BM=128 (2 t-slots/block), BN=128, K=4096 -----------------
// A = xbf[b][t][4096] bf16; B = UT[n][k]; C = XALL[t][b][8192], t=1..19
__global__ __launch_bounds__(256, 2)
void gemm_xu(const unsigned short* __restrict__ xbf,
             const unsigned short* __restrict__ UT,
             unsigned short* __restrict__ XALL)
{
    const int tid = threadIdx.x, lane = tid & 63, wid = tid >> 6;
    const int wr = wid >> 1, wc = wid & 1;
    const int nt = blockIdx.x, mt = blockIdx.y;      // nt<64, mt<10
    const int n0 = nt * 128;
    const int l15 = lane & 15, l4 = lane >> 4;

    __shared__ unsigned short As[8192];   // 128 x 64, swizzled
    __shared__ unsigned short Bs[8192];

    const int arow = tid >> 1, aseg = tid & 1;       // row 0..127, 32-k segment
    {   // nothing
    }
    int tg = 1 + mt * 2 + (arow >> 6);
    if (tg > 19) tg = 19;                            // tail clamp (store skipped)
    const unsigned short* Abase = xbf + (size_t)(arow & 63) * 81920 + (size_t)tg * 4096 + aseg * 32;
    const unsigned short* Bbase = UT + (size_t)(n0 + arow) * 4096 + aseg * 32;

    us8 ra[4], rb[4];
    auto load = [&](int kk) {
#pragma unroll
        for (int j = 0; j < 4; ++j) {
            ra[j] = *reinterpret_cast<const us8*>(Abase + kk + j * 8);
            rb[j] = *reinterpret_cast<const us8*>(Bbase + kk + j * 8);
        }
    };
    auto stage = [&]() {
#pragma unroll
        for (int j = 0; j < 4; ++j) {
            int byte = ((aseg * 4 + j) * 16) ^ ((arow & 7) << 4);
            *reinterpret_cast<us8*>(reinterpret_cast<char*>(As) + arow * 128 + byte) = ra[j];
            *reinterpret_cast<us8*>(reinterpret_cast<char*>(Bs) + arow * 128 + byte) = rb[j];
        }
    };

    v4f acc[4][4];
#pragma unroll
    for (int i = 0; i < 4; ++i)
#pragma unroll
        for (int j = 0; j < 4; ++j) acc[i][j] = (v4f){0.f, 0.f, 0.f, 0.f};

    load(0);
    for (int it = 0; it < 64; ++it) {
        __syncthreads();
        stage();
        __syncthreads();
        if (it + 1 < 64) load((it + 1) * 64);
#pragma unroll
        for (int ks = 0; ks < 2; ++ks) {
            const int kb = (ks * 32 + l4 * 8) * 2;
            v8bf af[4], bfr[4];
#pragma unroll
            for (int f = 0; f < 4; ++f) {
                int rowA = wr * 64 + f * 16 + l15;
                af[f] = *reinterpret_cast<const v8bf*>(reinterpret_cast<const char*>(As)
                          + rowA * 128 + (kb ^ ((rowA & 7) << 4)));
                int rowB = wc * 64 + f * 16 + l15;
                bfr[f] = *reinterpret_cast<const v8bf*>(reinterpret_cast<const char*>(Bs)
                          + rowB * 128 + (kb ^ ((rowB & 7) << 4)));
            }
#pragma unroll
            for (int fm = 0; fm < 4; ++fm)
#pragma unroll
                for (int fn = 0; fn < 4; ++fn)
                    acc[fm][fn] = __builtin_amdgcn_mfma_f32_16x16x32_bf16(af[fm], bfr[fn], acc[fm][fn], 0, 0, 0);
        }
    }
    const int tg2 = 1 + mt * 2 + wr;
    if (tg2 <= 19) {
        unsigned short* Cb = XALL + (size_t)tg2 * 524288;
#pragma unroll
        for (int fm = 0; fm < 4; ++fm)
#pragma unroll
            for (int fn = 0; fn < 4; ++fn)
#pragma unroll
                for (int r = 0; r < 4; ++r) {
                    int b = fm * 16 + l4 * 4 + r;
                    int col = n0 + wc * 64 + fn * 16 + l15;
                    Cb[(size_t)b * 8192 + col] = f2bf(acc[fm][fn][r]);
                }
    }
}

// ------- reservoir step (also h0): split-K 4 + fused last-block combine ----
// R6-proven 2-buf syncthreads pipeline; tiled B; NT hints on streaming traffic.
#define KZ 4
__global__ __launch_bounds__(256, 2)
void scan_step(const unsigned short* __restrict__ A, int lda,
               const unsigned short* __restrict__ BTiles, int ktiles,
               int kper,
               const unsigned short* __restrict__ xu,
               unsigned short* __restrict__ hnext,
               unsigned short* __restrict__ Hbf, int t,
               float* __restrict__ part,
               unsigned int* __restrict__ tickets)
{
    const int tid = threadIdx.x, lane = tid & 63, wid = tid >> 6;
    const int wr = wid >> 1, wc = wid & 1;
    const int nt = blockIdx.x & 127, kz = blockIdx.x >> 7;
    const int n0 = nt * 64, kstart = kz * kper;
    const int l15 = lane & 15, l4 = lane >> 4;
    const int nit = kper >> 6;

    __shared__ unsigned short smem[16384];   // 32 KB: 2 bufs x (A 8KB + B 8KB)
    char* base = reinterpret_cast<char*>(smem);

    const int srow = tid >> 3, sq = tid & 7;
    const int gslot = sq ^ (srow & 7);
    const unsigned short* Asrc = A + (size_t)srow * lda + kstart + gslot * 8;
    const unsigned short* Bsrc = BTiles
        + ((size_t)(nt * ktiles + kz * (kper >> 6))) * 4096 + tid * 8;

    auto stage = [&](int buf, int it) {
        char* dA = base + buf * 16384 + wid * 1024;
        char* dB = dA + 8192;
        const int kk = it * 64;
#pragma unroll
        for (int p = 0; p < 2; ++p) {
            __builtin_amdgcn_global_load_lds(
                (const __attribute__((address_space(1))) void*)(Asrc + kk + (size_t)p * 32 * lda),
                (__attribute__((address_space(3))) void*)(dA + p * 4096), 16, 0, 0);
            __builtin_amdgcn_global_load_lds(
                (const __attribute__((address_space(1))) void*)(Bsrc + (size_t)it * 4096 + p * 2048),
                (__attribute__((address_space(3))) void*)(dB + p * 4096), 16, 0, 0);
        }
    };

    v4f acc00 = {0.f, 0.f, 0.f, 0.f};
    v4f acc01 = acc00, acc10 = acc00, acc11 = acc00;

    stage(0, 0);
    for (int it = 0; it < nit; ++it) {
        const int cur = it & 1;
        __syncthreads();                             // stage(cur) landed; cur^1 free
        if (it + 1 < nit) stage(cur ^ 1, it + 1);
        const char* As = base + cur * 16384;
        const char* Bs = As + 8192;
#pragma unroll
        for (int ks = 0; ks < 2; ++ks) {
            const int kb = (ks * 32 + l4 * 8) * 2;
            v8bf a0, a1, b0, b1;
            { int row = wr * 32 + l15;      a0 = *reinterpret_cast<const v8bf*>(As + row * 128 + (kb ^ ((row & 7) << 4))); }
            { int row = wr * 32 + 16 + l15; a1 = *reinterpret_cast<const v8bf*>(As + row * 128 + (kb ^ ((row & 7) << 4))); }
            { int row = wc * 32 + l15;      b0 = *reinterpret_cast<const v8bf*>(Bs + row * 128 + (kb ^ ((row & 7) << 4))); }
            { int row = wc * 32 + 16 + l15; b1 = *reinterpret_cast<const v8bf*>(Bs + row * 128 + (kb ^ ((row & 7) << 4))); }
            acc00 = __builtin_amdgcn_mfma_f32_16x16x32_bf16(a0, b0, acc00, 0, 0, 0);
            acc01 = __builtin_amdgcn_mfma_f32_16x16x32_bf16(a0, b1, acc01, 0, 0, 0);
            acc10 = __builtin_amdgcn_mfma_f32_16x16x32_bf16(a1, b0, acc10, 0, 0, 0);
            acc11 = __builtin_amdgcn_mfma_f32_16x16x32_bf16(a1, b1, acc11, 0, 0, 0);
        }
    }

    // partial store (non-temporal: single-use, keep out of L3 so Wr stays hot)
    float* mypart = part + (size_t)kz * 524288;
#pragma unroll
    for (int r = 0; r < 4; ++r) {
        int row0 = wr * 32 + l4 * 4 + r;
        int col0 = n0 + wc * 32 + l15;
        __builtin_nontemporal_store(acc00[r], &mypart[(size_t)row0 * 8192 + col0]);
        __builtin_nontemporal_store(acc01[r], &mypart[(size_t)row0 * 8192 + col0 + 16]);
        __builtin_nontemporal_store(acc10[r], &mypart[(size_t)(row0 + 16) * 8192 + col0]);
        __builtin_nontemporal_store(acc11[r], &mypart[(size_t)(row0 + 16) * 8192 + col0 + 16]);
    }

    __shared__ int lastflag;
    __syncthreads();
    if (tid == 0) {
        unsigned int old = __hip_atomic_fetch_add(&tickets[nt], 1u,
                              __ATOMIC_ACQ_REL, __HIP_MEMORY_SCOPE_AGENT);
        lastflag = (old == KZ - 1);
    }
    __syncthreads();
    if (!lastflag) return;

    const int row = tid >> 2;
    const int c0 = n0 + (tid & 3) * 16;
    float pre[16];
    if (xu) {
        const us8* xp = reinterpret_cast<const us8*>(xu + (size_t)row * 8192 + c0);
        us8 x0 = __builtin_nontemporal_load(xp);
        us8 x1 = __builtin_nontemporal_load(xp + 1);
#pragma unroll
        for (int j = 0; j < 8; ++j) { pre[j] = bf2f(x0[j]); pre[8 + j] = bf2f(x1[j]); }
    } else {
#pragma unroll
        for (int j = 0; j < 16; ++j) pre[j] = 0.f;
    }
#pragma unroll
    for (int z = 0; z < KZ; ++z) {
        const float* pp = part + (size_t)z * 524288 + (size_t)row * 8192 + c0;
#pragma unroll
        for (int q = 0; q < 4; ++q) {
            v4f v = __builtin_nontemporal_load(reinterpret_cast<const v4f*>(pp + q * 4));
#pragma unroll
            for (int e = 0; e < 4; ++e) pre[q * 4 + e] += v[e];
        }
    }
    us8 o0, o1;
#pragma unroll
    for (int j = 0; j < 16; ++j) {
        unsigned short hb = f2bf(tanhf(pre[j]));
        if (j < 8) o0[j] = hb; else o1[j - 8] = hb;
        int col = c0 + j;
        __builtin_nontemporal_store(hb,
            &Hbf[(((size_t)row * 20 + t) * 1024 + (col & 1023)) * 8 + (col >> 10)]);
    }
    *reinterpret_cast<us8*>(hnext + (size_t)row * 8192 + c0)     = o0;  // hot next step
    *reinterpret_cast<us8*>(hnext + (size_t)row * 8192 + c0 + 8) = o1;
    if (tid == 0)
        __hip_atomic_store(&tickets[nt], 0u, __ATOMIC_RELAXED, __HIP_MEMORY_SCOPE_AGENT);
}

// ------- weight conversion to GEMM k-order bf16 ----------------------------
__global__ __launch_bounds__(256)
void cvt_w1(const float* __restrict__ w, unsigned short* __restrict__ o,
            unsigned int* __restrict__ tickets)
{
    if (blockIdx.x == 0 && threadIdx.x < 128) tickets[threadIdx.x] = 0;
    int idx = blockIdx.x * 256 + threadIdx.x;    // 64*224
    if (idx >= 64 * 224) return;
    int co = idx / 224, k = idx % 224;
    int g = k >> 3, ci = k & 7;
    float v = 0.f;
    if (g < 27) {
        int dt = g / 9, rr = g % 9, dy = rr / 3, dx = rr % 3;
        v = w[(((co * 8 + ci) * 3 + dt) * 3 + dy) * 3 + dx];
    }
    o[idx] = f2bf(v);
}
__global__ __launch_bounds__(256)
void cvt_w2(const float* __restrict__ w, unsigned short* __restrict__ o)
{
    int idx = blockIdx.x * 256 + threadIdx.x;    // 128*3072
    if (idx >= 128 * 3072) return;
    int co = idx / 3072, k = idx % 3072;
    int g = k >> 6, ci = k & 63;
    int dt = g >> 4, dy = (g >> 2) & 3, dx = g & 3;
    o[idx] = f2bf(w[(((co * 64 + ci) * 3 + dt) * 4 + dy) * 4 + dx]);
}

// ------- conv1: H[b][t][1024][8] -> y1[b][t][256][64] ----------------------
__global__ __launch_bounds__(256, 2)
void conv1_kernel(const unsigned short* __restrict__ H,
                  const unsigned short* __restrict__ w1,  // [64][224]
                  const float* __restrict__ bias,
                  unsigned short* __restrict__ y1)
{
    const int b = blockIdx.x, t = blockIdx.y;
    const int tid = threadIdx.x, lane = tid & 63, wid = tid >> 6;
    __shared__ unsigned short in_s[3 * 33 * 33 * 8];   // 52272 B
    __shared__ unsigned short w_s[64 * 224];           // stride 448 B

    for (int i = tid; i < 13068; i += 256) reinterpret_cast<unsigned int*>(in_s)[i] = 0;
    __syncthreads();
    for (int idx = tid; idx < 3 * 1024; idx += 256) {
        int dt = idx >> 10, rem = idx & 1023;
        int iy = rem >> 5, ix = rem & 31;
        int ts = t + dt - 1;
        if (ts >= 0 && ts < 20) {
            us8 v = *reinterpret_cast<const us8*>(H + (((size_t)b * 20 + ts) * 1024 + rem) * 8);
            int byte = ((dt * 33 + iy + 1) * 33 + (ix + 1)) * 16;
            *reinterpret_cast<us8*>(reinterpret_cast<char*>(in_s) + sw(byte)) = v;
        }
    }
    for (int idx = tid; idx < 64 * 28; idx += 256) {
        int co = idx / 28, j = idx % 28;
        us8 v = *reinterpret_cast<const us8*>(w1 + co * 224 + j * 8);
        *reinterpret_cast<us8*>(reinterpret_cast<char*>(w_s) + sw(co * 448 + j * 16)) = v;
    }
    __syncthreads();

    const int l15 = lane & 15, l4 = lane >> 4;
    const int m_lo = wid * 64 + l15;
    v4f z4 = {0.f, 0.f, 0.f, 0.f};
    v4f acc[4][4];                              // [fm][fc]
#pragma unroll
    for (int i = 0; i < 4; ++i)
#pragma unroll
        for (int j = 0; j < 4; ++j) acc[i][j] = z4;

#pragma unroll
    for (int ks = 0; ks < 7; ++ks) {
        int g = ks * 4 + l4;
        int gc = g < 27 ? g : 26;               // pad group: weights are zero
        int dt = gc / 9, rr = gc % 9, dy = rr / 3, dx = rr % 3;
        v8bf ap[4], aw[4];
#pragma unroll
        for (int fm = 0; fm < 4; ++fm) {
            int m = fm * 16 + m_lo;
            int py = m >> 4, px = m & 15;
            int byte = ((dt * 33 + 2 * py + dy) * 33 + 2 * px + dx) * 16;
            ap[fm] = *reinterpret_cast<const v8bf*>(reinterpret_cast<const char*>(in_s) + sw(byte));
        }
        int kb2 = (ks * 32 + l4 * 8) * 2;
#pragma unroll
        for (int fc = 0; fc < 4; ++fc) {
            int co = fc * 16 + l15;
            aw[fc] = *reinterpret_cast<const v8bf*>(reinterpret_cast<const char*>(w_s) + sw(co * 448 + kb2));
        }
#pragma unroll
        for (int fm = 0; fm < 4; ++fm)
#pragma unroll
            for (int fc = 0; fc < 4; ++fc)
                acc[fm][fc] = __builtin_amdgcn_mfma_f32_16x16x32_bf16(ap[fm], aw[fc], acc[fm][fc], 0, 0, 0);
    }
#pragma unroll
    for (int fm = 0; fm < 4; ++fm)
#pragma unroll
        for (int fc = 0; fc < 4; ++fc)
#pragma unroll
            for (int r = 0; r < 4; ++r) {
                int m  = wid * 64 + fm * 16 + l4 * 4 + r;
                int co = fc * 16 + l15;
                float v = acc[fm][fc][r] + bias[co];
                v = v > 0.f ? v : 0.01f * v;
                y1[(((size_t)b * 20 + t) * 256 + m) * 64 + co] = f2bf(v);
            }
}

// ------- conv2: y1[b][t][256][64] -> y2[b][128][20][49] --------------------
__global__ __launch_bounds__(512, 2)
void conv2_kernel(const unsigned short* __restrict__ y1,
                  const unsigned short* __restrict__ w2,  // [128][3072]
                  const float* __restrict__ bias,
                  unsigned short* __restrict__ y2)
{
    const int b = blockIdx.x, t = blockIdx.y;
    const int tid = threadIdx.x, lane = tid & 63, wid = tid >> 6;
    const int wc = wid >> 1, wr = wid & 1;
    __shared__ unsigned short in_s[256 * 64];   // parity-cell layout, 32KB
    __shared__ unsigned short w_s[128 * 128];   // 128-k chunk, 32KB
    const int l15 = lane & 15, l4 = lane >> 4;

    const int m0v = wr * 32 + l15, m1v = m0v + 16;
    const int m0c = m0v < 49 ? m0v : 48, m1c = m1v < 49 ? m1v : 48;
    const int py0 = m0c / 7, px0 = m0c - py0 * 7;
    const int py1 = m1c / 7, px1 = m1c - py1 * 7;

    v4f acc[2][2];                              // [fc][fm]
#pragma unroll
    for (int i = 0; i < 2; ++i)
#pragma unroll
        for (int j = 0; j < 2; ++j) acc[i][j] = (v4f){0.f, 0.f, 0.f, 0.f};

    for (int dt = 0; dt < 3; ++dt) {
        int ts = t + dt - 1;
        __syncthreads();                        // in_s reuse guard
        if (ts < 0 || ts >= 20) continue;       // zero contribution (uniform)
#pragma unroll
        for (int p = 0; p < 4; ++p) {
            int idx = tid + p * 512;            // 2048 us8
            int slot = idx >> 3, c8 = idx & 7;
            int yy = slot >> 4, xx = slot & 15;
            us8 v = *reinterpret_cast<const us8*>(y1 + (((size_t)b * 20 + ts) * 256 + slot) * 64 + c8 * 8);
            int cell = ((yy & 1) * 2 + (xx & 1)) * 64 + (yy >> 1) * 8 + (xx >> 1);
            int byte = cell * 128 + ((c8 * 16) ^ (((cell ^ (cell >> 3)) & 7) << 4));
            *reinterpret_cast<us8*>(reinterpret_cast<char*>(in_s) + byte) = v;
        }
        for (int kc = 0; kc < 8; ++kc) {        // 8 x 128 k per dt
            __syncthreads();
#pragma unroll
            for (int p = 0; p < 4; ++p) {
                int idx = tid + p * 512;        // 2048 us8
                int co = idx >> 4, j = idx & 15;
                us8 v = *reinterpret_cast<const us8*>(w2 + (size_t)co * 3072 + dt * 1024 + kc * 128 + j * 8);
                *reinterpret_cast<us8*>(reinterpret_cast<char*>(w_s) + co * 256 + ((j * 16) ^ ((co & 7) << 4))) = v;
            }
            __syncthreads();
#pragma unroll
            for (int ks = 0; ks < 4; ++ks) {
                int klocal = ks * 32 + l4 * 8;
                int kk = kc * 128 + klocal;     // 0..1023 within dt
                int dy = (kk >> 8) & 3, dx = (kk >> 6) & 3, ci0 = kk & 63;
                v8bf aw[2], bp[2];
#pragma unroll
                for (int fc = 0; fc < 2; ++fc) {
                    int co = wc * 32 + fc * 16 + l15;
                    aw[fc] = *reinterpret_cast<const v8bf*>(reinterpret_cast<const char*>(w_s)
                               + co * 256 + ((klocal * 2) ^ ((co & 7) << 4)));
                }
                int plane = ((dy & 1) << 1) | (dx & 1);
                int c0 = plane * 64 + (py0 + (dy >> 1)) * 8 + px0 + (dx >> 1);
                int c1 = plane * 64 + (py1 + (dy >> 1)) * 8 + px1 + (dx >> 1);
                bp[0] = *reinterpret_cast<const v8bf*>(reinterpret_cast<const char*>(in_s)
                          + c0 * 128 + ((ci0 * 2) ^ (((c0 ^ (c0 >> 3)) & 7) << 4)));
                bp[1] = *reinterpret_cast<const v8bf*>(reinterpret_cast<const char*>(in_s)
                          + c1 * 128 + ((ci0 * 2) ^ (((c1 ^ (c1 >> 3)) & 7) << 4)));
#pragma unroll
                for (int fc = 0; fc < 2; ++fc)
#pragma unroll
                    for (int fm = 0; fm < 2; ++fm)
                        acc[fc][fm] = __builtin_amdgcn_mfma_f32_16x16x32_bf16(aw[fc], bp[fm], acc[fc][fm], 0, 0, 0);
            }
        }
    }
#pragma unroll
    for (int fc = 0; fc < 2; ++fc)
#pragma unroll
        for (int fm = 0; fm < 2; ++fm)
#pragma unroll
            for (int r = 0; r < 4; ++r) {
                int co = wc * 32 + fc * 16 + l4 * 4 + r;
                int m  = wr * 32 + fm * 16 + l15;
                if (m < 49) {
                    float v = acc[fc][fm][r] + bias[co];
                    v = v > 0.f ? v : 0.01f * v;
                    y2[(((size_t)b * 128 + co) * 20 + t) * 49 + m] = f2bf(v);
                }
            }
}

// ------- linear epilogue: sum 7 split-K parts, +bias, split mu/logvar ------
__global__ __launch_bounds__(256)
void lin_epi(const float* __restrict__ linC, const float* __restrict__ lb,
             float* __restrict__ out)
{
    int i = blockIdx.x * 256 + threadIdx.x;      // 0..327679
    int m = i >> 8, n = i & 255;
    float v = lb[n];
#pragma unroll
    for (int z = 0; z < 7; ++z) v += linC[(size_t)z * 327680 + i];
    size_t o = (n < 128) ? ((size_t)m * 128 + n) : (163840 + (size_t)m * 128 + (n - 128));
    out[o] = v;
}

extern "C" void kernel_launch(void* const* d_in, const int* in_sizes, int n_in,
                              void* d_out, int out_size, void* d_ws, size_t ws_size,
                              hipStream_t stream)
{
    const float* x   = (const float*)d_in[0];
    const float* Win = (const float*)d_in[1];
    const float* U   = (const float*)d_in[2];
    const float* Wr  = (const float*)d_in[3];
    const float* c1w = (const float*)d_in[4];
    const float* c1b = (const float*)d_in[5];
    const float* c2w = (const float*)d_in[6];
    const float* c2b = (const float*)d_in[7];
    const float* lw  = (const float*)d_in[8];
    const float* lb  = (const float*)d_in[9];

    char* ws = (char*)d_ws;
    unsigned short* WrTile = (unsigned short*)(ws);                 // 128 MB tiled
    unsigned short* xbf  = (unsigned short*)(ws);                   // 10.5 MB, dead before WrTile
    unsigned short* WT   = (unsigned short*)(ws + 134217728ll);     // 64 MB (WinTile then UT)
    unsigned short* y1   = (unsigned short*)(ws + 134217728ll);     // 41.9 MB (after xU)
    unsigned short* y2   = (unsigned short*)(ws + 176160768ll);     // 16.1 MB
    unsigned short* XALL = (unsigned short*)(ws + 201326592ll);     // 21 MB [20][64][8192]
    unsigned short* Hbf  = (unsigned short*)(ws + 222298112ll);     // 21 MB [b][t][1024][8]
    unsigned short* hb0  = (unsigned short*)(ws + 243269632ll);     // 1 MB
    unsigned short* hb1  = (unsigned short*)(ws + 244318208ll);     // 1 MB
    float*          part = (float*)        (ws + 245366784ll);      // 8.4 MB (h0 + scan)
    float*          linC = (float*)        (ws + 245366784ll);      // 9.2 MB (aliases part)
    unsigned short* w1bf = (unsigned short*)(ws + 254541824ll);     // 28 KB
    unsigned short* w2bf = (unsigned short*)(ws + 254570496ll);     // 768 KB
    unsigned int*   tick = (unsigned int*) (ws + 255356928ll);      // 512 B
    float*          out  = (float*)d_out;

    cvt_w1<<<56, 256, 0, stream>>>(c1w, w1bf, tick);
    cvt_w2<<<1536, 256, 0, stream>>>(c2w, w2bf);
    cvt_x<<<2560, 256, 0, stream>>>(x, xbf);

    // h0 = tanh(x0 @ Win): WinTile (tiled transpose) + KZ=4 pipelined step
    transpose_f32_bf16_tiled<<<dim3(128, 64), 256, 0, stream>>>(Win, WT, 8192, 64);
    scan_step<<<512, 256, 0, stream>>>(xbf, 81920, WT, 64, 1024,
                                       (const unsigned short*)nullptr, hb0, Hbf, 0, part, tick);

    // xU = x[:,1:] @ U  — BM=128 (2 t/block) halves UT re-streams
    transpose_f32_bf16<<<dim3(128, 64), 256, 0, stream>>>(U, WT, 4096, 8192);
    gemm_xu<<<dim3(64, 10), 256, 0, stream>>>(xbf, WT, XALL);

    // reservoir scan t=1..19: per-step fused split-K kernel, tiled Wr + NT hints
    transpose_f32_bf16_tiled<<<dim3(128, 128), 256, 0, stream>>>(Wr, WrTile, 8192, 128);
    for (int t = 1; t < 20; ++t) {
        const unsigned short* hprev = (t & 1) ? hb0 : hb1;
        unsigned short*       hnext = (t & 1) ? hb1 : hb0;
        scan_step<<<512, 256, 0, stream>>>(hprev, 8192, WrTile, 128, 2048,
                                           XALL + (size_t)t * 524288, hnext, Hbf, t, part, tick);
    }

    conv1_kernel<<<dim3(64, 20), 256, 0, stream>>>(Hbf, w1bf, c1b, y1);
    conv2_kernel<<<dim3(64, 20), 512, 0, stream>>>(y1, w2bf, c2b, y2);

    // linear head: A = y2 as [1280][6272] bf16, BT = lin_w fp32, split-K 7
    gemm_bt<128, false, false, true><<<dim3(2, 20, 7), 256, 0, stream>>>(
        y2, 6272, 6272 * 64, lw, 6272, linC, 256, 896, 327680ll);
    lin_epi<<<1280, 256, 0, stream>>>(linC, lb, out);
}

// Round 15
// 1454.705 us; speedup vs baseline: 1.2451x; 1.1141x over previous
//
#include <hip/hip_runtime.h>

typedef __bf16 v8bf __attribute__((ext_vector_type(8)));
typedef float  v4f  __attribute__((ext_vector_type(4)));
typedef unsigned short us8 __attribute__((ext_vector_type(8)));

__device__ __forceinline__ float bf2f(unsigned short u) {
    union { unsigned int i; float f; } v; v.i = ((unsigned int)u) << 16; return v.f;
}
__device__ __forceinline__ unsigned short f2bf(float f) {
    union { float f; unsigned int i; } v; v.f = f;
    return (unsigned short)((v.i + 0x7fffu + ((v.i >> 16) & 1u)) >> 16);
}
// address involution swizzle: XOR 16B-slot bits (4-6) with bits 7-9. Bijective.
__device__ __forceinline__ int sw(int b) { return b ^ (((b >> 7) & 7) << 4); }

// ------- transpose+downcast: dst[n][k] = bf16(src[k][n]); K,N mult of 64 ----
__global__ __launch_bounds__(256)
void transpose_f32_bf16(const float* __restrict__ src,
                        unsigned short* __restrict__ dst, int K, int N)
{
    __shared__ unsigned short tile[64][72];
    const int tid = threadIdx.x;
    const int c0 = blockIdx.x * 64, r0 = blockIdx.y * 64;
    const int tr = tid >> 2, tc4 = tid & 3;
    const float* sp = src + (size_t)(r0 + tr) * N + c0 + tc4 * 16;
#pragma unroll
    for (int j = 0; j < 4; ++j) {
        v4f f = *reinterpret_cast<const v4f*>(sp + j * 4);
#pragma unroll
        for (int e = 0; e < 4; ++e) tile[tr][tc4 * 16 + j * 4 + e] = f2bf(f[e]);
    }
    __syncthreads();
    const int ow = tid >> 3, och = tid & 7;
#pragma unroll
    for (int p = 0; p < 2; ++p) {
        int orow = p * 32 + ow;
        us8 o;
#pragma unroll
        for (int e = 0; e < 8; ++e) o[e] = tile[och * 8 + e][orow];
        *reinterpret_cast<us8*>(dst + (size_t)(c0 + orow) * K + r0 + och * 8) = o;
    }
}

// ------- generic GEMM (h0 / xU / linear); B transposed (BT[n][k]) ----------
template<int BN, bool STORE_BF16, bool AF32, bool BF32>
__global__ __launch_bounds__(256, 2)
void gemm_bt(const void* __restrict__ Ap, int lda_lo, int lda_hi,
             const void* __restrict__ BTp, int ldb,
             void* __restrict__ Cout, int ldc,
             int ksub, long long csplit_stride)
{
    constexpr int FN  = BN / 32;
    constexpr int BCH = BN / 32;
    const int tid = threadIdx.x;
    const int lane = tid & 63, wid = tid >> 6;
    const int wr = wid >> 1, wc = wid & 1;
    const int nt = blockIdx.x, mt = blockIdx.y, kz = blockIdx.z;
    const int n0 = nt * BN;
    const int kstart = kz * ksub;

    __shared__ unsigned short smem[(64 + BN) * 64];
    char* As = reinterpret_cast<char*>(smem);
    char* Bs = reinterpret_cast<char*>(smem + 64 * 64);

    const unsigned short* A16 = (const unsigned short*)Ap;
    const float*          A32 = (const float*)Ap;
    const unsigned short* B16 = (const unsigned short*)BTp;
    const float*          B32 = (const float*)BTp;

    const int arow = AF32 ? (tid >> 2) : (tid >> 3);
    const int aq   = AF32 ? (tid & 3) : (tid & 7);
    const float* Ab32 = A32 + (size_t)arow * lda_lo + (size_t)mt * lda_hi + kstart + aq * 16;
    const unsigned short* Ab16 = A16 + (size_t)arow * lda_lo + (size_t)mt * lda_hi + kstart + aq * 8;
    const int brow = tid >> 3, bq = tid & 7;
    const float* Bb32 = B32 + (size_t)(n0 + brow) * ldb + kstart + bq * 8;
    const unsigned short* Bb16 = B16 + (size_t)(n0 + brow) * ldb + kstart + bq * 8;

    v4f fa[4];
    us8 ra[2];
    v4f fb[BCH][2];
    us8 rb[BCH];

    auto load = [&](int kk) {
        if (AF32) {
#pragma unroll
            for (int j = 0; j < 4; ++j)
                fa[j] = *reinterpret_cast<const v4f*>(Ab32 + kk + j * 4);
        } else {
#pragma unroll
            for (int p = 0; p < 2; ++p)
                ra[p] = *reinterpret_cast<const us8*>(Ab16 + (size_t)(p * 32) * lda_lo + kk);
        }
        if (BF32) {
#pragma unroll
            for (int p = 0; p < BCH; ++p) {
                fb[p][0] = *reinterpret_cast<const v4f*>(Bb32 + (size_t)(p * 32) * ldb + kk);
                fb[p][1] = *reinterpret_cast<const v4f*>(Bb32 + (size_t)(p * 32) * ldb + kk + 4);
            }
        } else {
#pragma unroll
            for (int p = 0; p < BCH; ++p)
                rb[p] = *reinterpret_cast<const us8*>(Bb16 + (size_t)(p * 32) * ldb + kk);
        }
    };
    auto stage = [&]() {
        if (AF32) {
#pragma unroll
            for (int h = 0; h < 2; ++h) {
                us8 v;
#pragma unroll
                for (int e = 0; e < 8; ++e) v[e] = f2bf(fa[h * 2 + (e >> 2)][e & 3]);
                *reinterpret_cast<us8*>(As + arow * 128 + (((aq * 2 + h) * 16) ^ ((arow & 7) << 4))) = v;
            }
        } else {
#pragma unroll
            for (int p = 0; p < 2; ++p)
                *reinterpret_cast<us8*>(As + (arow + p * 32) * 128 + ((aq * 16) ^ ((arow & 7) << 4))) = ra[p];
        }
#pragma unroll
        for (int p = 0; p < BCH; ++p) {
            us8 v;
            if (BF32) {
#pragma unroll
                for (int e = 0; e < 8; ++e) v[e] = f2bf(fb[p][e >> 2][e & 3]);
            } else v = rb[p];
            *reinterpret_cast<us8*>(Bs + (brow + p * 32) * 128 + ((bq * 16) ^ ((brow & 7) << 4))) = v;
        }
    };

    v4f z4 = {0.f, 0.f, 0.f, 0.f};
    v4f acc[2][FN];
#pragma unroll
    for (int i = 0; i < 2; ++i)
#pragma unroll
        for (int j = 0; j < FN; ++j) acc[i][j] = z4;

    const int l15 = lane & 15, l4 = lane >> 4;
    const int nk = ksub / 64;
    load(0);
    for (int it = 0; it < nk; ++it) {
        __syncthreads();
        stage();
        __syncthreads();
        if (it + 1 < nk) load((it + 1) * 64);
#pragma unroll
        for (int ks = 0; ks < 2; ++ks) {
            const int kb = (ks * 32 + l4 * 8) * 2;
            v8bf af[2], bfr[FN];
#pragma unroll
            for (int fm = 0; fm < 2; ++fm) {
                int row = wr * 32 + fm * 16 + l15;
                af[fm] = *reinterpret_cast<const v8bf*>(As + row * 128 + (kb ^ ((row & 7) << 4)));
            }
#pragma unroll
            for (int fn = 0; fn < FN; ++fn) {
                int row = wc * (BN / 2) + fn * 16 + l15;
                bfr[fn] = *reinterpret_cast<const v8bf*>(Bs + row * 128 + (kb ^ ((row & 7) << 4)));
            }
#pragma unroll
            for (int fm = 0; fm < 2; ++fm)
#pragma unroll
                for (int fn = 0; fn < FN; ++fn)
                    acc[fm][fn] = __builtin_amdgcn_mfma_f32_16x16x32_bf16(af[fm], bfr[fn], acc[fm][fn], 0, 0, 0);
        }
    }
    const long long m0 = (long long)mt * 64;
#pragma unroll
    for (int fm = 0; fm < 2; ++fm)
#pragma unroll
        for (int fn = 0; fn < FN; ++fn)
#pragma unroll
            for (int r = 0; r < 4; ++r) {
                long long row = m0 + wr * 32 + fm * 16 + l4 * 4 + r;
                long long col = n0 + wc * (BN / 2) + fn * 16 + l15;
                long long idx = (long long)kz * csplit_stride + row * ldc + col;
                if (STORE_BF16) reinterpret_cast<unsigned short*>(Cout)[idx] = f2bf(acc[fm][fn][r]);
                else            reinterpret_cast<float*>(Cout)[idx]          = acc[fm][fn][r];
            }
}

// ------- combine for h0: pre = sum(parts)+xu; h = tanh(pre); scatter -------
__global__ __launch_bounds__(256)
void scan_combine(const float* __restrict__ part, int nparts,
                  const unsigned short* __restrict__ xu,
                  unsigned short* __restrict__ hcur,
                  unsigned short* __restrict__ Hbf, int t)
{
    int i = blockIdx.x * 256 + threadIdx.x;       // over 64*8192
    float pre = xu ? bf2f(xu[i]) : 0.f;
    for (int z = 0; z < nparts; ++z) pre += part[(size_t)z * 524288 + i];
    float h = tanhf(pre);
    unsigned short hb = f2bf(h);
    hcur[i] = hb;
    int b = i >> 13, r = i & 8191;
    int c = r >> 10, pp = r & 1023;
    Hbf[(((size_t)b * 20 + t) * 1024 + pp) * 8 + c] = hb;   // [b][t][1024][8]
}

// ------- one reservoir step: split-K GEMM + fused last-block combine -------
// grid 512 = 128 nt x 4 kz; gload_lds double-buffered staging (R6 champion)
#define KZ 4
__global__ __launch_bounds__(256, 2)
void scan_step(const unsigned short* __restrict__ WrT,    // [8192][8192]
               const unsigned short* __restrict__ hprev,  // [64][8192] bf16
               const unsigned short* __restrict__ xu,     // [64][8192] bf16
               unsigned short* __restrict__ hnext,
               unsigned short* __restrict__ Hbf, int t,
               float* __restrict__ part,                  // [KZ][64][8192]
               unsigned int* __restrict__ tickets)        // [128]
{
    const int tid = threadIdx.x, lane = tid & 63, wid = tid >> 6;
    const int wr = wid >> 1, wc = wid & 1;
    const int nt = blockIdx.x & 127, kz = blockIdx.x >> 7;
    const int n0 = nt * 64, kstart = kz * 2048;
    const int l15 = lane & 15, l4 = lane >> 4;

    __shared__ unsigned short smem[16384];   // 32 KB: 2 bufs x (A 8KB + B 8KB)
    char* base = reinterpret_cast<char*>(smem);

    const int srow = tid >> 3, sq = tid & 7;
    const int gslot = sq ^ (srow & 7);               // (srow+32)&7 == srow&7
    const unsigned short* Asrc = hprev + (size_t)srow * 8192 + kstart + gslot * 8;
    const unsigned short* Bsrc = WrT + (size_t)(n0 + srow) * 8192 + kstart + gslot * 8;

    auto stage = [&](int buf, int kk) {
        char* dA = base + buf * 16384 + wid * 1024;  // wave-uniform LDS base
        char* dB = dA + 8192;
#pragma unroll
        for (int p = 0; p < 2; ++p) {
            __builtin_amdgcn_global_load_lds(
                (const __attribute__((address_space(1))) void*)(Asrc + kk + (size_t)p * 32 * 8192),
                (__attribute__((address_space(3))) void*)(dA + p * 4096), 16, 0, 0);
            __builtin_amdgcn_global_load_lds(
                (const __attribute__((address_space(1))) void*)(Bsrc + kk + (size_t)p * 32 * 8192),
                (__attribute__((address_space(3))) void*)(dB + p * 4096), 16, 0, 0);
        }
    };

    v4f acc00 = {0.f, 0.f, 0.f, 0.f};
    v4f acc01 = acc00, acc10 = acc00, acc11 = acc00;

    stage(0, 0);
    for (int it = 0; it < 32; ++it) {
        const int cur = it & 1;
        __syncthreads();                             // stage(cur) landed; cur^1 free
        if (it + 1 < 32) stage(cur ^ 1, (it + 1) * 64);
        const char* As = base + cur * 16384;
        const char* Bs = As + 8192;
#pragma unroll
        for (int ks = 0; ks < 2; ++ks) {
            const int kb = (ks * 32 + l4 * 8) * 2;
            v8bf a0, a1, b0, b1;
            { int row = wr * 32 + l15;      a0 = *reinterpret_cast<const v8bf*>(As + row * 128 + (kb ^ ((row & 7) << 4))); }
            { int row = wr * 32 + 16 + l15; a1 = *reinterpret_cast<const v8bf*>(As + row * 128 + (kb ^ ((row & 7) << 4))); }
            { int row = wc * 32 + l15;      b0 = *reinterpret_cast<const v8bf*>(Bs + row * 128 + (kb ^ ((row & 7) << 4))); }
            { int row = wc * 32 + 16 + l15; b1 = *reinterpret_cast<const v8bf*>(Bs + row * 128 + (kb ^ ((row & 7) << 4))); }
            acc00 = __builtin_amdgcn_mfma_f32_16x16x32_bf16(a0, b0, acc00, 0, 0, 0);
            acc01 = __builtin_amdgcn_mfma_f32_16x16x32_bf16(a0, b1, acc01, 0, 0, 0);
            acc10 = __builtin_amdgcn_mfma_f32_16x16x32_bf16(a1, b0, acc10, 0, 0, 0);
            acc11 = __builtin_amdgcn_mfma_f32_16x16x32_bf16(a1, b1, acc11, 0, 0, 0);
        }
    }

    // partial store (plain stores: short reuse distance -> L2-local)
    float* mypart = part + (size_t)kz * 524288;
#pragma unroll
    for (int r = 0; r < 4; ++r) {
        int row0 = wr * 32 + l4 * 4 + r;
        int col0 = n0 + wc * 32 + l15;
        mypart[(size_t)row0 * 8192 + col0]             = acc00[r];
        mypart[(size_t)row0 * 8192 + col0 + 16]        = acc01[r];
        mypart[(size_t)(row0 + 16) * 8192 + col0]      = acc10[r];
        mypart[(size_t)(row0 + 16) * 8192 + col0 + 16] = acc11[r];
    }

    // split-K ticket: last-arriving block for this nt does the combine
    __shared__ int lastflag;
    __syncthreads();                                 // all partial stores drained
    if (tid == 0) {
        unsigned int old = __hip_atomic_fetch_add(&tickets[nt], 1u,
                              __ATOMIC_ACQ_REL, __HIP_MEMORY_SCOPE_AGENT);
        lastflag = (old == KZ - 1);
    }
    __syncthreads();
    if (!lastflag) return;

    // combine strip nt: rows 0..63, cols n0..n0+63; 16 cols/thread
    const int row = tid >> 2;
    const int c0 = n0 + (tid & 3) * 16;
    float pre[16];
    {
        const us8* xp = reinterpret_cast<const us8*>(xu + (size_t)row * 8192 + c0);
        us8 x0 = xp[0], x1 = xp[1];
#pragma unroll
        for (int j = 0; j < 8; ++j) { pre[j] = bf2f(x0[j]); pre[8 + j] = bf2f(x1[j]); }
    }
#pragma unroll
    for (int z = 0; z < KZ; ++z) {
        const float* pp = part + (size_t)z * 524288 + (size_t)row * 8192 + c0;
#pragma unroll
        for (int q = 0; q < 4; ++q) {
            v4f v = *reinterpret_cast<const v4f*>(pp + q * 4);
#pragma unroll
            for (int e = 0; e < 4; ++e) pre[q * 4 + e] += v[e];
        }
    }
    us8 o0, o1;
#pragma unroll
    for (int j = 0; j < 16; ++j) {
        unsigned short hb = f2bf(tanhf(pre[j]));
        if (j < 8) o0[j] = hb; else o1[j - 8] = hb;
        int col = c0 + j;
        Hbf[(((size_t)row * 20 + t) * 1024 + (col & 1023)) * 8 + (col >> 10)] = hb;
    }
    *reinterpret_cast<us8*>(hnext + (size_t)row * 8192 + c0)     = o0;
    *reinterpret_cast<us8*>(hnext + (size_t)row * 8192 + c0 + 8) = o1;
    if (tid == 0)
        __hip_atomic_store(&tickets[nt], 0u, __ATOMIC_RELAXED, __HIP_MEMORY_SCOPE_AGENT);
}

// ------- weight conversion to GEMM k-order bf16 ----------------------------
__global__ __launch_bounds__(256)
void cvt_w1(const float* __restrict__ w, unsigned short* __restrict__ o,
            unsigned int* __restrict__ tickets)
{
    if (blockIdx.x == 0 && threadIdx.x < 128) tickets[threadIdx.x] = 0;
    int idx = blockIdx.x * 256 + threadIdx.x;    // 64*224
    if (idx >= 64 * 224) return;
    int co = idx / 224, k = idx % 224;
    int g = k >> 3, ci = k & 7;
    float v = 0.f;
    if (g < 27) {
        int dt = g / 9, rr = g % 9, dy = rr / 3, dx = rr % 3;
        v = w[(((co * 8 + ci) * 3 + dt) * 3 + dy) * 3 + dx];
    }
    o[idx] = f2bf(v);
}
__global__ __launch_bounds__(256)
void cvt_w2(const float* __restrict__ w, unsigned short* __restrict__ o)
{
    int idx = blockIdx.x * 256 + threadIdx.x;    // 128*3072
    if (idx >= 128 * 3072) return;
    int co = idx / 3072, k = idx % 3072;
    int g = k >> 6, ci = k & 63;
    int dt = g >> 4, dy = (g >> 2) & 3, dx = g & 3;
    o[idx] = f2bf(w[(((co * 64 + ci) * 3 + dt) * 4 + dy) * 4 + dx]);
}

// ------- conv1: H[b][t][1024][8] -> y1[b][t][256][64] ----------------------
__global__ __launch_bounds__(256, 2)
void conv1_kernel(const unsigned short* __restrict__ H,
                  const unsigned short* __restrict__ w1,  // [64][224]
                  const float* __restrict__ bias,
                  unsigned short* __restrict__ y1)
{
    const int b = blockIdx.x, t = blockIdx.y;
    const int tid = threadIdx.x, lane = tid & 63, wid = tid >> 6;
    __shared__ unsigned short in_s[3 * 33 * 33 * 8];   // 52272 B
    __shared__ unsigned short w_s[64 * 224];           // stride 448 B

    for (int i = tid; i < 13068; i += 256) reinterpret_cast<unsigned int*>(in_s)[i] = 0;
    __syncthreads();
    for (int idx = tid; idx < 3 * 1024; idx += 256) {
        int dt = idx >> 10, rem = idx & 1023;
        int iy = rem >> 5, ix = rem & 31;
        int ts = t + dt - 1;
        if (ts >= 0 && ts < 20) {
            us8 v = *reinterpret_cast<const us8*>(H + (((size_t)b * 20 + ts) * 1024 + rem) * 8);
            int byte = ((dt * 33 + iy + 1) * 33 + (ix + 1)) * 16;
            *reinterpret_cast<us8*>(reinterpret_cast<char*>(in_s) + sw(byte)) = v;
        }
    }
    for (int idx = tid; idx < 64 * 28; idx += 256) {
        int co = idx / 28, j = idx % 28;
        us8 v = *reinterpret_cast<const us8*>(w1 + co * 224 + j * 8);
        *reinterpret_cast<us8*>(reinterpret_cast<char*>(w_s) + sw(co * 448 + j * 16)) = v;
    }
    __syncthreads();

    const int l15 = lane & 15, l4 = lane >> 4;
    const int m_lo = wid * 64 + l15;
    v4f z4 = {0.f, 0.f, 0.f, 0.f};
    v4f acc[4][4];                              // [fm][fc]
#pragma unroll
    for (int i = 0; i < 4; ++i)
#pragma unroll
        for (int j = 0; j < 4; ++j) acc[i][j] = z4;

#pragma unroll
    for (int ks = 0; ks < 7; ++ks) {
        int g = ks * 4 + l4;
        int gc = g < 27 ? g : 26;               // pad group: weights are zero
        int dt = gc / 9, rr = gc % 9, dy = rr / 3, dx = rr % 3;
        v8bf ap[4], aw[4];
#pragma unroll
        for (int fm = 0; fm < 4; ++fm) {
            int m = fm * 16 + m_lo;
            int py = m >> 4, px = m & 15;
            int byte = ((dt * 33 + 2 * py + dy) * 33 + 2 * px + dx) * 16;
            ap[fm] = *reinterpret_cast<const v8bf*>(reinterpret_cast<const char*>(in_s) + sw(byte));
        }
        int kb2 = (ks * 32 + l4 * 8) * 2;
#pragma unroll
        for (int fc = 0; fc < 4; ++fc) {
            int co = fc * 16 + l15;
            aw[fc] = *reinterpret_cast<const v8bf*>(reinterpret_cast<const char*>(w_s) + sw(co * 448 + kb2));
        }
#pragma unroll
        for (int fm = 0; fm < 4; ++fm)
#pragma unroll
            for (int fc = 0; fc < 4; ++fc)
                acc[fm][fc] = __builtin_amdgcn_mfma_f32_16x16x32_bf16(ap[fm], aw[fc], acc[fm][fc], 0, 0, 0);
    }
#pragma unroll
    for (int fm = 0; fm < 4; ++fm)
#pragma unroll
        for (int fc = 0; fc < 4; ++fc)
#pragma unroll
            for (int r = 0; r < 4; ++r) {
                int m  = wid * 64 + fm * 16 + l4 * 4 + r;
                int co = fc * 16 + l15;
                float v = acc[fm][fc][r] + bias[co];
                v = v > 0.f ? v : 0.01f * v;
                y1[(((size_t)b * 20 + t) * 256 + m) * 64 + co] = f2bf(v);
            }
}

// ------- conv2: y1[b][t][256][64] -> y2[b][128][20][49] --------------------
__global__ __launch_bounds__(512, 2)
void conv2_kernel(const unsigned short* __restrict__ y1,
                  const unsigned short* __restrict__ w2,  // [128][3072]
                  const float* __restrict__ bias,
                  unsigned short* __restrict__ y2)
{
    const int b = blockIdx.x, t = blockIdx.y;
    const int tid = threadIdx.x, lane = tid & 63, wid = tid >> 6;
    const int wc = wid >> 1, wr = wid & 1;
    __shared__ unsigned short in_s[256 * 64];   // parity-cell layout, 32KB
    __shared__ unsigned short w_s[128 * 128];   // 128-k chunk, 32KB
    const int l15 = lane & 15, l4 = lane >> 4;

    const int m0v = wr * 32 + l15, m1v = m0v + 16;
    const int m0c = m0v < 49 ? m0v : 48, m1c = m1v < 49 ? m1v : 48;
    const int py0 = m0c / 7, px0 = m0c - py0 * 7;
    const int py1 = m1c / 7, px1 = m1c - py1 * 7;

    v4f acc[2][2];                              // [fc][fm]
#pragma unroll
    for (int i = 0; i < 2; ++i)
#pragma unroll
        for (int j = 0; j < 2; ++j) acc[i][j] = (v4f){0.f, 0.f, 0.f, 0.f};

    for (int dt = 0; dt < 3; ++dt) {
        int ts = t + dt - 1;
        __syncthreads();                        // in_s reuse guard
        if (ts < 0 || ts >= 20) continue;       // zero contribution (uniform)
#pragma unroll
        for (int p = 0; p < 4; ++p) {
            int idx = tid + p * 512;            // 2048 us8
            int slot = idx >> 3, c8 = idx & 7;
            int yy = slot >> 4, xx = slot & 15;
            us8 v = *reinterpret_cast<const us8*>(y1 + (((size_t)b * 20 + ts) * 256 + slot) * 64 + c8 * 8);
            int cell = ((yy & 1) * 2 + (xx & 1)) * 64 + (yy >> 1) * 8 + (xx >> 1);
            int byte = cell * 128 + ((c8 * 16) ^ (((cell ^ (cell >> 3)) & 7) << 4));
            *reinterpret_cast<us8*>(reinterpret_cast<char*>(in_s) + byte) = v;
        }
        for (int kc = 0; kc < 8; ++kc) {        // 8 x 128 k per dt
            __syncthreads();
#pragma unroll
            for (int p = 0; p < 4; ++p) {
                int idx = tid + p * 512;        // 2048 us8
                int co = idx >> 4, j = idx & 15;
                us8 v = *reinterpret_cast<const us8*>(w2 + (size_t)co * 3072 + dt * 1024 + kc * 128 + j * 8);
                *reinterpret_cast<us8*>(reinterpret_cast<char*>(w_s) + co * 256 + ((j * 16) ^ ((co & 7) << 4))) = v;
            }
            __syncthreads();
#pragma unroll
            for (int ks = 0; ks < 4; ++ks) {
                int klocal = ks * 32 + l4 * 8;
                int kk = kc * 128 + klocal;     // 0..1023 within dt
                int dy = (kk >> 8) & 3, dx = (kk >> 6) & 3, ci0 = kk & 63;
                v8bf aw[2], bp[2];
#pragma unroll
                for (int fc = 0; fc < 2; ++fc) {
                    int co = wc * 32 + fc * 16 + l15;
                    aw[fc] = *reinterpret_cast<const v8bf*>(reinterpret_cast<const char*>(w_s)
                               + co * 256 + ((klocal * 2) ^ ((co & 7) << 4)));
                }
                int plane = ((dy & 1) << 1) | (dx & 1);
                int c0 = plane * 64 + (py0 + (dy >> 1)) * 8 + px0 + (dx >> 1);
                int c1 = plane * 64 + (py1 + (dy >> 1)) * 8 + px1 + (dx >> 1);
                bp[0] = *reinterpret_cast<const v8bf*>(reinterpret_cast<const char*>(in_s)
                          + c0 * 128 + ((ci0 * 2) ^ (((c0 ^ (c0 >> 3)) & 7) << 4)));
                bp[1] = *reinterpret_cast<const v8bf*>(reinterpret_cast<const char*>(in_s)
                          + c1 * 128 + ((ci0 * 2) ^ (((c1 ^ (c1 >> 3)) & 7) << 4)));
#pragma unroll
                for (int fc = 0; fc < 2; ++fc)
#pragma unroll
                    for (int fm = 0; fm < 2; ++fm)
                        acc[fc][fm] = __builtin_amdgcn_mfma_f32_16x16x32_bf16(aw[fc], bp[fm], acc[fc][fm], 0, 0, 0);
            }
        }
    }
#pragma unroll
    for (int fc = 0; fc < 2; ++fc)
#pragma unroll
        for (int fm = 0; fm < 2; ++fm)
#pragma unroll
            for (int r = 0; r < 4; ++r) {
                int co = wc * 32 + fc * 16 + l4 * 4 + r;
                int m  = wr * 32 + fm * 16 + l15;
                if (m < 49) {
                    float v = acc[fc][fm][r] + bias[co];
                    v = v > 0.f ? v : 0.01f * v;
                    y2[(((size_t)b * 128 + co) * 20 + t) * 49 + m] = f2bf(v);
                }
            }
}

// ------- linear epilogue: sum 7 split-K parts, +bias, split mu/logvar ------
__global__ __launch_bounds__(256)
void lin_epi(const float* __restrict__ linC, const float* __restrict__ lb,
             float* __restrict__ out)
{
    int i = blockIdx.x * 256 + threadIdx.x;      // 0..327679
    int m = i >> 8, n = i & 255;
    float v = lb[n];
#pragma unroll
    for (int z = 0; z < 7; ++z) v += linC[(size_t)z * 327680 + i];
    size_t o = (n < 128) ? ((size_t)m * 128 + n) : (163840 + (size_t)m * 128 + (n - 128));
    out[o] = v;
}

extern "C" void kernel_launch(void* const* d_in, const int* in_sizes, int n_in,
                              void* d_out, int out_size, void* d_ws, size_t ws_size,
                              hipStream_t stream)
{
    const float* x   = (const float*)d_in[0];
    const float* Win = (const float*)d_in[1];
    const float* U   = (const float*)d_in[2];
    const float* Wr  = (const float*)d_in[3];
    const float* c1w = (const float*)d_in[4];
    const float* c1b = (const float*)d_in[5];
    const float* c2w = (const float*)d_in[6];
    const float* c2b = (const float*)d_in[7];
    const float* lw  = (const float*)d_in[8];
    const float* lb  = (const float*)d_in[9];

    char* ws = (char*)d_ws;
    unsigned short* WrT  = (unsigned short*)(ws);                   // 128 MB
    unsigned short* WT   = (unsigned short*)(ws + 134217728ll);     // 64 MB (WinT then UT)
    unsigned short* y1   = (unsigned short*)(ws + 134217728ll);     // 41.9 MB (after xU)
    unsigned short* y2   = (unsigned short*)(ws + 176160768ll);     // 12.85 MB
    unsigned short* XALL = (unsigned short*)(ws + 201326592ll);     // 21 MB [20][64][8192]
    unsigned short* Hbf  = (unsigned short*)(ws + 222298112ll);     // 21 MB [b][t][1024][8]
    unsigned short* hb0  = (unsigned short*)(ws + 243269632ll);     // 1 MB
    unsigned short* hb1  = (unsigned short*)(ws + 244318208ll);     // 1 MB
    float*          part = (float*)        (ws + 245366784ll);      // 8.4 MB (h0 + scan)
    float*          linC = (float*)        (ws + 245366784ll);      // 9.2 MB (aliases part)
    unsigned short* w1bf = (unsigned short*)(ws + 254541824ll);     // 28 KB
    unsigned short* w2bf = (unsigned short*)(ws + 254570496ll);     // 768 KB
    unsigned int*   tick = (unsigned int*) (ws + 255356928ll);      // 512 B
    float*          out  = (float*)d_out;

    cvt_w1<<<56, 256, 0, stream>>>(c1w, w1bf, tick);
    cvt_w2<<<1536, 256, 0, stream>>>(c2w, w2bf);

    // h0 = tanh(x0 @ Win): split-K 4 + combine
    transpose_f32_bf16<<<dim3(128, 64), 256, 0, stream>>>(Win, WT, 4096, 8192);
    gemm_bt<64, false, true, false><<<dim3(128, 1, 4), 256, 0, stream>>>(
        x, 81920, 0, WT, 4096, part, 8192, 1024, 524288ll);
    scan_combine<<<2048, 256, 0, stream>>>(part, 4, (const unsigned short*)nullptr, hb0, Hbf, 0);

    // xU = x[:,1:] @ U
    transpose_f32_bf16<<<dim3(128, 64), 256, 0, stream>>>(U, WT, 4096, 8192);
    gemm_bt<128, true, true, false><<<dim3(64, 19, 1), 256, 0, stream>>>(
        x + 4096, 81920, 4096, WT, 4096, XALL + 524288, 8192, 4096, 0ll);

    // reservoir scan t=1..19: per-step fused split-K kernel
    transpose_f32_bf16<<<dim3(128, 128), 256, 0, stream>>>(Wr, WrT, 8192, 8192);
    for (int t = 1; t < 20; ++t) {
        const unsigned short* hprev = (t & 1) ? hb0 : hb1;
        unsigned short*       hnext = (t & 1) ? hb1 : hb0;
        scan_step<<<512, 256, 0, stream>>>(WrT, hprev, XALL + (size_t)t * 524288,
                                           hnext, Hbf, t, part, tick);
    }

    conv1_kernel<<<dim3(64, 20), 256, 0, stream>>>(Hbf, w1bf, c1b, y1);
    conv2_kernel<<<dim3(64, 20), 512, 0, stream>>>(y1, w2bf, c2b, y2);

    // linear head: A = y2 as [1280][6272] bf16, BT = lin_w fp32, split-K 7
    gemm_bt<128, false, false, true><<<dim3(2, 20, 7), 256, 0, stream>>>(
        y2, 6272, 6272 * 64, lw, 6272, linC, 256, 896, 327680ll);
    lin_epi<<<1280, 256, 0, stream>>>(linC, lb, out);
}